// Round 15
// baseline (306.146 us; speedup 1.0000x reference)
//
#include <hip/hip_runtime.h>
#include <hip/hip_bf16.h>

#define B_ 256
#define N_ 784
#define E_ 6272
#define C_ 32
#define H_ 512
#define NK 25088            // N_*C_  (K of fc1; wf1t row stride)
#define KP 800              // padded src-dim AND padded dest-dim for Adj
#define S_SPLIT 28

typedef __attribute__((ext_vector_type(8))) short short8;
typedef __attribute__((ext_vector_type(4))) float f32x4;

__device__ __forceinline__ float elu1(float v) {
  return v > 0.f ? v : (__expf(v) - 1.f);
}

__device__ __forceinline__ unsigned short bf16b(float v) {
  __hip_bfloat16 h = __float2bfloat16(v);
  return *reinterpret_cast<unsigned short*>(&h);
}

__device__ __forceinline__ unsigned int pk2(float lo, float hi) {
  return (unsigned int)bf16b(lo) | ((unsigned int)bf16b(hi) << 16);
}

// ---- K0: block 0 = CSR; blocks 1..79 = zero Adj; blocks 80.. = Wf1 T part1 ----
__global__ __launch_bounds__(1024) void k_prep(
    const int* __restrict__ erow, const int* __restrict__ ecol,
    const float* __restrict__ eval, const float* __restrict__ Wf1,
    int* __restrict__ row_ptr, int* __restrict__ col_s, float* __restrict__ val_s,
    __hip_bfloat16* __restrict__ adj, __hip_bfloat16* __restrict__ wf1t) {
  const int t = threadIdx.x;
  if (blockIdx.x == 0) {
    __shared__ int cnt[N_];
    __shared__ int off[N_];
    __shared__ int bufA[1024];
    __shared__ int bufB[1024];
    if (t < N_) cnt[t] = 0;
    __syncthreads();
    for (int e = t; e < E_; e += 1024) atomicAdd(&cnt[erow[e]], 1);
    __syncthreads();
    bufA[t] = (t < N_) ? cnt[t] : 0;
    __syncthreads();
    int* src = bufA; int* dst = bufB;
    for (int d = 1; d < 1024; d <<= 1) {
      int v = src[t];
      if (t >= d) v += src[t - d];
      dst[t] = v;
      __syncthreads();
      int* tmp = src; src = dst; dst = tmp;
    }
    if (t < N_) {
      int ex = src[t] - cnt[t];
      off[t] = ex;
      row_ptr[t] = ex;
    }
    if (t == 0) row_ptr[N_] = E_;
    __syncthreads();
    for (int e = t; e < E_; e += 1024) {
      int r = erow[e];
      int p = atomicAdd(&off[r], 1);
      col_s[p] = ecol[e];
      val_s[p] = eval[e];
    }
  } else if (blockIdx.x <= 79) {
    // zero Adj [800][800] bf16 = 1,280,000 B
    size_t off16 = ((size_t)(blockIdx.x - 1) * 1024 + t) * 16;
    if (off16 < (size_t)KP * KP * 2) {
      int4 z = {0, 0, 0, 0};
      *reinterpret_cast<int4*>(reinterpret_cast<char*>(adj) + off16) = z;
    }
  } else {
    // Wf1 [25088][512] f32 -> wf1t [512][25088] bf16, k in [0, 12544)
    __shared__ float tile[64][65];
    int bid = blockIdx.x - 80;                 // 0..1567
    int k0 = (bid % 196) * 64, n0 = (bid / 196) * 64;
#pragma unroll
    for (int it = 0; it < 4; ++it) {
      int idx = it * 1024 + t;
      int k = idx >> 6, n = idx & 63;
      tile[k][n] = Wf1[(size_t)(k0 + k) * H_ + n0 + n];
    }
    __syncthreads();
#pragma unroll
    for (int it = 0; it < 2; ++it) {
      int idx = it * 1024 + t;
      int n = idx >> 5, kp = idx & 31;
      unsigned int v = pk2(tile[2 * kp][n], tile[2 * kp + 1][n]);
      *reinterpret_cast<unsigned int*>(
          wf1t + (size_t)(n0 + n) * NK + k0 + 2 * kp) = v;
    }
  }
}

// ---- K1: blocks [0,256): exact-f32 spmm1 + W1 + elu -> h1T[bc][src] (padded)
//      blocks [256,260): Adj scatter from CSR (row-owned, duplicate-safe)
//      blocks [260,1828): Wf1 T part2 (k in [12544, 25088)) ----
__global__ __launch_bounds__(256) void k_h1T(
    const float* __restrict__ x, const int* __restrict__ row_ptr,
    const int* __restrict__ col_s, const float* __restrict__ val_s,
    const float* __restrict__ W1, const float* __restrict__ b1,
    const float* __restrict__ Wf1, __hip_bfloat16* __restrict__ adj,
    __hip_bfloat16* __restrict__ wf1t, __hip_bfloat16* __restrict__ h1T) {
  __shared__ float sm[64 * 65];       // union: xls[784]+aggls[784] | 64x65 tile
  int bid = blockIdx.x, t = threadIdx.x;
  if (bid < B_) {
    int b = bid;
    float* xls = sm;
    float* aggls = sm + N_;
    for (int i = t; i < N_; i += 256) xls[i] = x[(size_t)b * N_ + i];
    __syncthreads();
    for (int i = t; i < N_; i += 256) {
      int e0 = row_ptr[i], e1 = row_ptr[i + 1];
      float a = 0.f;
      for (int e = e0; e < e1; ++e) a = fmaf(val_s[e], xls[col_s[e]], a);
      aggls[i] = a;
    }
    __syncthreads();
#pragma unroll
    for (int c = 0; c < C_; ++c) {
      __hip_bfloat16* rowp = h1T + (size_t)(b * C_ + c) * KP;
      float wc = W1[c], bc = b1[c];
      for (int i = t; i < KP / 2; i += 256) {
        int n = 2 * i;
        float v0 = (n < N_) ? elu1(fmaf(aggls[n], wc, bc)) : 0.f;
        float v1 = (n + 1 < N_) ? elu1(fmaf(aggls[n + 1], wc, bc)) : 0.f;
        *reinterpret_cast<unsigned int*>(rowp + n) = pk2(v0, v1);
      }
    }
  } else if (bid < B_ + 4) {
    int n = (bid - B_) * 256 + t;
    if (n < N_) {
      int e0 = row_ptr[n], e1 = row_ptr[n + 1];
      for (int e = e0; e < e1; ++e) {
        __hip_bfloat16* p = adj + (size_t)n * KP + col_s[e];
        float cur = __bfloat162float(*p);
        *p = __float2bfloat16(cur + val_s[e]);
      }
    }
  } else {
    // Wf1 transpose: k0 in [12544, 25088), 64x64 tiles with 256 threads
    int bid2 = bid - (B_ + 4);                 // 0..1567
    int k0 = 12544 + (bid2 % 196) * 64, n0 = (bid2 / 196) * 64;
    float (*tile)[65] = reinterpret_cast<float(*)[65]>(sm);
#pragma unroll
    for (int it = 0; it < 16; ++it) {
      int idx = it * 256 + t;
      int kk = idx >> 6, nn = idx & 63;
      tile[kk][nn] = Wf1[(size_t)(k0 + kk) * H_ + n0 + nn];
    }
    __syncthreads();
#pragma unroll
    for (int it = 0; it < 8; ++it) {
      int idx = it * 256 + t;
      int nn = idx >> 5, kp = idx & 31;
      unsigned int v = pk2(tile[2 * kp][nn], tile[2 * kp + 1][nn]);
      *reinterpret_cast<unsigned int*>(
          wf1t + (size_t)(n0 + nn) * NK + k0 + 2 * kp) = v;
    }
  }
}

// ---- K2: spmm2 as dense MFMA GEMM + W2 + elu -> flat --------------------------
// C[m=dest 800pad][n=bc 32] = sum_k Adj[m][k] * h1T[n][k], K=800 (25 steps).
// grid (256 batches, 2 m-halves); block = 320 threads = 5 waves; wave owns 5
// m-frags (half covers 25 frags = 400 rows). Live set ~105 VGPR -> no spill.
// B (50KB) staged once via global_load_lds; A from L2 via 2-deep asm ring,
// vmcnt(5), never 0 mid-loop. Epilogue: acc->LDS, W2 in-register, bf16->flat.
__global__ __launch_bounds__(320, 1) void k_gemm2(
    const __hip_bfloat16* __restrict__ adj, const __hip_bfloat16* __restrict__ h1T,
    const float* __restrict__ W2, const float* __restrict__ b2,
    __hip_bfloat16* __restrict__ flat) {
  __shared__ alignas(16) unsigned char lds[61952];
  // [0,51200): B frags (50 x 1KB) | reused [0,57600): epilogue 5w x 5fm x 2304B
  // [57600,61824): W2 [32][33] f32 ; [61824,61952): b2
  int b = blockIdx.x, h = blockIdx.y;
  int tid = threadIdx.x;
  int w = tid >> 6, l = tid & 63;
  int r = l & 15, g = l >> 4;

  float* w2ls = reinterpret_cast<float*>(lds + 57600);
  float* b2ls = reinterpret_cast<float*>(lds + 61824);
  for (int i = tid; i < 1024; i += 320)
    w2ls[(i >> 5) * 33 + (i & 31)] = W2[i];
  if (tid < 32) b2ls[tid] = b2[tid];

  // stage B: 50 fragments (fn in {0,1} x ks in [0,25)); wave w stages w*10+i
#pragma unroll
  for (int i = 0; i < 10; ++i) {
    int f = w * 10 + i;
    int fn = f / 25, ks = f - fn * 25;
    __builtin_amdgcn_global_load_lds(
        (const __attribute__((address_space(1))) unsigned int*)
            (h1T + (size_t)(b * C_ + fn * 16 + r) * KP + ks * 32 + g * 8),
        (__attribute__((address_space(3))) unsigned int*)(lds + f * 1024 + l * 16),
        16, 0, 0);
  }
  __syncthreads();   // drains vmcnt+lgkmcnt; B ready, W2/b2 ready

  int rowbase = (h * 25 + w * 5) * 16 + r;
  const __hip_bfloat16* pa[5];
#pragma unroll
  for (int fm = 0; fm < 5; ++fm)
    pa[fm] = adj + (size_t)(rowbase + fm * 16) * KP + g * 8;

  f32x4 acc[5][2];
#pragma unroll
  for (int i = 0; i < 5; ++i)
#pragma unroll
    for (int j = 0; j < 2; ++j) acc[i][j] = (f32x4){0.f, 0.f, 0.f, 0.f};

  int4 va[2][5];

#define ALOAD(dst, ptr, imm)                                                  \
  asm volatile("global_load_dwordx4 %0, %1, off offset:%2"                    \
               : "=v"(dst) : "v"(ptr), "n"(imm))
#define AISSUE(s) do {                                                        \
    _Pragma("unroll")                                                         \
    for (int fm = 0; fm < 5; ++fm)                                            \
      ALOAD(va[(s) & 1][fm], pa[fm], (s) * 64);                               \
  } while (0)
#define AWAIT(n) do {                                                         \
    asm volatile("s_waitcnt vmcnt(%0)" :: "n"(n) : "memory");                 \
    __builtin_amdgcn_sched_barrier(0);                                        \
  } while (0)
#define ASTEP(t) do {                                                         \
    AWAIT((t) < 24 ? 5 : 0);                                                  \
    short8 _b0 = *reinterpret_cast<const short8*>(lds + (t) * 1024 + l * 16); \
    short8 _b1 = *reinterpret_cast<const short8*>(lds + (25 + (t)) * 1024 + l * 16); \
    _Pragma("unroll")                                                         \
    for (int fm = 0; fm < 5; ++fm) {                                          \
      short8 _a = *reinterpret_cast<short8*>(&va[(t) & 1][fm]);               \
      acc[fm][0] = __builtin_amdgcn_mfma_f32_16x16x32_bf16(_a, _b0, acc[fm][0], 0, 0, 0); \
      acc[fm][1] = __builtin_amdgcn_mfma_f32_16x16x32_bf16(_a, _b1, acc[fm][1], 0, 0, 0); \
    }                                                                         \
    if ((t) + 2 < 25) AISSUE((t) + 2);                                        \
  } while (0)

  AISSUE(0); AISSUE(1);
  ASTEP(0);  ASTEP(1);  ASTEP(2);  ASTEP(3);  ASTEP(4);
  ASTEP(5);  ASTEP(6);  ASTEP(7);  ASTEP(8);  ASTEP(9);
  ASTEP(10); ASTEP(11); ASTEP(12); ASTEP(13); ASTEP(14);
  ASTEP(15); ASTEP(16); ASTEP(17); ASTEP(18); ASTEP(19);
  ASTEP(20); ASTEP(21); ASTEP(22); ASTEP(23); ASTEP(24);

#undef ALOAD
#undef AISSUE
#undef AWAIT
#undef ASTEP

  __syncthreads();   // all waves done reading B before epilogue reuses [0,57600)

  // spill acc to per-wave LDS tiles: [fm][16 rows][36 cols] f32
  float* epf = reinterpret_cast<float*>(lds + w * 11520);
#pragma unroll
  for (int fm = 0; fm < 5; ++fm)
#pragma unroll
    for (int fn = 0; fn < 2; ++fn)
#pragma unroll
      for (int q = 0; q < 4; ++q)
        epf[fm * 576 + (g * 4 + q) * 36 + fn * 16 + r] = acc[fm][fn][q];
  __syncthreads();

  int row = l >> 2, cq = l & 3;   // lane -> (row in frag, c-quarter)
  float o[5][8];
#pragma unroll
  for (int fm = 0; fm < 5; ++fm)
#pragma unroll
    for (int j = 0; j < 8; ++j) o[fm][j] = b2ls[cq * 8 + j];

#pragma unroll
  for (int cb = 0; cb < 8; ++cb) {          // c blocks of 4
    float w2r[4][8];
#pragma unroll
    for (int cc = 0; cc < 4; ++cc)
#pragma unroll
      for (int j = 0; j < 8; ++j)
        w2r[cc][j] = w2ls[(cb * 4 + cc) * 33 + cq * 8 + j];
#pragma unroll
    for (int fm = 0; fm < 5; ++fm) {
      f32x4 a = *reinterpret_cast<f32x4*>(&epf[fm * 576 + row * 36 + cb * 4]);
#pragma unroll
      for (int cc = 0; cc < 4; ++cc)
#pragma unroll
        for (int j = 0; j < 8; ++j)
          o[fm][j] = fmaf(a[cc], w2r[cc][j], o[fm][j]);
    }
  }

#pragma unroll
  for (int fm = 0; fm < 5; ++fm) {
    int dest = (h * 25 + w * 5 + fm) * 16 + row;
    if (dest < N_) {
      union { unsigned short u[8]; int4 v; } ob;
#pragma unroll
      for (int j = 0; j < 8; ++j) ob.u[j] = bf16b(elu1(o[fm][j]));
      *reinterpret_cast<int4*>(flat + (size_t)b * NK + dest * C_ + cq * 8) = ob.v;
    }
  }
}

// ---------------- K3: fc1 split-K MFMA GEMM via global_load_lds pipeline ----------
// (unchanged from round 10 -- verified working)
__global__ __launch_bounds__(256, 2) void k_fc1(
    const __hip_bfloat16* __restrict__ flat, const __hip_bfloat16* __restrict__ wf1t,
    float* __restrict__ partial) {
  __shared__ unsigned char lds[3 * 24576];
  int raw = blockIdx.x;
  int bid = (raw & 7) * 56 + (raw >> 3);      // bijective XCD swizzle (448 = 8*56)
  int s = bid >> 4, r16 = bid & 15;
  int m0 = (r16 & 1) * 128;
  int n0 = (r16 >> 1) * 64;
  int k0 = s * 896;
  int tid = threadIdx.x;
  int w = tid >> 6, l = tid & 63;
  int r = l & 15, g = l >> 4;

  const __hip_bfloat16* src[6];
  int ldsoff[6];
#pragma unroll
  for (int j = 0; j < 6; ++j) {
    int reg = w * 6 + j;
    ldsoff[j] = reg * 1024 + l * 16;
    if (reg < 16) {
      int fmg = reg >> 1, ks = reg & 1;
      src[j] = flat + (size_t)(m0 + fmg * 16 + r) * NK + (k0 + ks * 32 + g * 8);
    } else {
      int fng = (reg - 16) >> 1, ks = reg & 1;
      src[j] = wf1t + (size_t)(n0 + fng * 16 + r) * NK + (k0 + ks * 32 + g * 8);
    }
  }

  f32x4 acc[4][2];
#pragma unroll
  for (int i = 0; i < 4; ++i)
#pragma unroll
    for (int j = 0; j < 2; ++j) acc[i][j] = (f32x4){0.f, 0.f, 0.f, 0.f};

#define GLOAD_LDS(gp, lp)                                                     \
  __builtin_amdgcn_global_load_lds(                                           \
      (const __attribute__((address_space(1))) unsigned int*)(gp),            \
      (__attribute__((address_space(3))) unsigned int*)(lp), 16, 0, 0)
#define STAGE(t, buf) do {                                                    \
    _Pragma("unroll")                                                         \
    for (int j = 0; j < 6; ++j)                                               \
      GLOAD_LDS(src[j] + (t) * 64, &lds[(buf) * 24576 + ldsoff[j]]);          \
  } while (0)
#define VWAIT(n) do {                                                         \
    asm volatile("s_waitcnt vmcnt(%0)" :: "n"(n) : "memory");                 \
    __builtin_amdgcn_sched_barrier(0);                                        \
  } while (0)
#define BAR() do {                                                            \
    __builtin_amdgcn_s_barrier();                                             \
    __builtin_amdgcn_sched_barrier(0);                                        \
  } while (0)
#define COMPUTE(buf) do {                                                     \
    const unsigned char* bb = &lds[(buf) * 24576];                            \
    short8 af[4][2], bf[2][2];                                                \
    _Pragma("unroll")                                                         \
    for (int fm = 0; fm < 4; ++fm)                                            \
      _Pragma("unroll")                                                       \
      for (int ks = 0; ks < 2; ++ks)                                          \
        af[fm][ks] = *reinterpret_cast<const short8*>(                        \
            bb + (((4 * (w & 1) + fm) * 2 + ks) << 10) + l * 16);             \
    _Pragma("unroll")                                                         \
    for (int fn = 0; fn < 2; ++fn)                                            \
      _Pragma("unroll")                                                       \
      for (int ks = 0; ks < 2; ++ks)                                          \
        bf[fn][ks] = *reinterpret_cast<const short8*>(                        \
            bb + ((16 + (2 * (w >> 1) + fn) * 2 + ks) << 10) + l * 16);       \
    _Pragma("unroll")                                                         \
    for (int ks = 0; ks < 2; ++ks)                                            \
      _Pragma("unroll")                                                       \
      for (int fn = 0; fn < 2; ++fn)                                          \
        _Pragma("unroll")                                                     \
        for (int fm = 0; fm < 4; ++fm)                                        \
          acc[fm][fn] = __builtin_amdgcn_mfma_f32_16x16x32_bf16(              \
              af[fm][ks], bf[fn][ks], acc[fm][fn], 0, 0, 0);                  \
  } while (0)
#define STEP(t) do {                                                          \
    VWAIT((t) < 13 ? 6 : 0);                                                  \
    BAR();                                                                    \
    if ((t) + 2 <= 13) STAGE((t) + 2, ((t) + 2) % 3);                         \
    COMPUTE((t) % 3);                                                         \
  } while (0)

  STAGE(0, 0);
  STAGE(1, 1);
  STEP(0);  STEP(1);  STEP(2);  STEP(3);  STEP(4);  STEP(5);  STEP(6);
  STEP(7);  STEP(8);  STEP(9);  STEP(10); STEP(11); STEP(12); STEP(13);

#undef GLOAD_LDS
#undef STAGE
#undef VWAIT
#undef BAR
#undef COMPUTE
#undef STEP

  int wm = (w & 1) * 64, wn = (w >> 1) * 32;
  float* p = partial + (size_t)s * (256 * 512);
#pragma unroll
  for (int fm = 0; fm < 4; ++fm)
#pragma unroll
    for (int fn = 0; fn < 2; ++fn)
#pragma unroll
      for (int q = 0; q < 4; ++q) {
        int m = m0 + wm + fm * 16 + g * 4 + q;
        int n = n0 + wn + fn * 16 + r;
        p[m * 512 + n] = acc[fm][fn][q];
      }
}

// ---------------- K4: reduce partials + bias + relu + fc2 + softmax ----------------
__global__ __launch_bounds__(512) void k_head(
    const float* __restrict__ partial, const float* __restrict__ bf1,
    const float* __restrict__ Wf2, const float* __restrict__ bf2,
    float* __restrict__ out) {
  __shared__ float red[8][12];
  int b = blockIdx.x;
  int t = threadIdx.x;
  float v = bf1[t];
#pragma unroll
  for (int s = 0; s < S_SPLIT; ++s)
    v += partial[(size_t)s * (256 * 512) + b * 512 + t];
  v = fmaxf(v, 0.f);
  float pacc[10];
#pragma unroll
  for (int j = 0; j < 10; ++j) pacc[j] = v * Wf2[t * 10 + j];
#pragma unroll
  for (int j = 0; j < 10; ++j)
#pragma unroll
    for (int d = 32; d > 0; d >>= 1)
      pacc[j] += __shfl_down(pacc[j], d);
  int wv = t >> 6, ln = t & 63;
  if (ln == 0) {
#pragma unroll
    for (int j = 0; j < 10; ++j) red[wv][j] = pacc[j];
  }
  __syncthreads();
  if (t == 0) {
    float lg[10];
    float m = -1e30f;
#pragma unroll
    for (int j = 0; j < 10; ++j) {
      float z = bf2[j];
#pragma unroll
      for (int wq = 0; wq < 8; ++wq) z += red[wq][j];
      lg[j] = z;
      m = fmaxf(m, z);
    }
    float sum = 0.f;
#pragma unroll
    for (int j = 0; j < 10; ++j) { lg[j] = __expf(lg[j] - m); sum += lg[j]; }
    float inv = 1.f / sum;
#pragma unroll
    for (int j = 0; j < 10; ++j) out[b * 10 + j] = lg[j] * inv;
  }
}

extern "C" void kernel_launch(void* const* d_in, const int* in_sizes, int n_in,
                              void* d_out, int out_size, void* d_ws, size_t ws_size,
                              hipStream_t stream) {
  const float* x    = (const float*)d_in[0];
  const int*   erow = (const int*)d_in[1];
  const int*   ecol = (const int*)d_in[2];
  const float* ev   = (const float*)d_in[3];
  const float* W1   = (const float*)d_in[4];
  const float* b1   = (const float*)d_in[5];
  const float* W2   = (const float*)d_in[6];
  const float* b2   = (const float*)d_in[7];
  const float* Wf1  = (const float*)d_in[8];
  const float* bf1  = (const float*)d_in[9];
  const float* Wf2  = (const float*)d_in[10];
  const float* bf2  = (const float*)d_in[11];
  float* out = (float*)d_out;

  const size_t partial_bytes = (size_t)S_SPLIT * 256 * 512 * 4;   // 14,680,064
  const size_t flat_bytes    = (size_t)B_ * NK * 2;               // 12,845,056
  const size_t wf1t_bytes    = (size_t)H_ * NK * 2;               // 25,690,112
  const size_t h1t_bytes     = (size_t)B_ * C_ * KP * 2;          // 13,107,200
  const size_t adj_bytes     = (size_t)KP * KP * 2;               //  1,280,000

  // disjoint layout (~67.6 MB; ws is ~268 MB)
  char* ws = (char*)d_ws;
  float* partial          = (float*)ws;
  __hip_bfloat16* flat    = (__hip_bfloat16*)(ws + partial_bytes);
  __hip_bfloat16* wf1t    = (__hip_bfloat16*)(ws + partial_bytes + flat_bytes);
  __hip_bfloat16* h1T     = (__hip_bfloat16*)(ws + partial_bytes + flat_bytes + wf1t_bytes);
  __hip_bfloat16* adj     = (__hip_bfloat16*)(ws + partial_bytes + flat_bytes + wf1t_bytes + h1t_bytes);
  char* tail = ws + partial_bytes + flat_bytes + wf1t_bytes + h1t_bytes + adj_bytes;
  int*   row_ptr = (int*)tail;
  int*   col_s   = (int*)(tail + 3152);
  float* val_s   = (float*)(tail + 3152 + E_ * 4);

  hipLaunchKernelGGL(k_prep, dim3(1 + 79 + 1568), dim3(1024), 0, stream,
                     erow, ecol, ev, Wf1, row_ptr, col_s, val_s, adj, wf1t);
  hipLaunchKernelGGL(k_h1T, dim3(B_ + 4 + 1568), dim3(256), 0, stream,
                     x, row_ptr, col_s, val_s, W1, b1, Wf1, adj, wf1t, h1T);
  hipLaunchKernelGGL(k_gemm2, dim3(B_, 2), dim3(320), 0, stream,
                     adj, h1T, W2, b2, flat);
  hipLaunchKernelGGL(k_fc1, dim3(S_SPLIT * 16), dim3(256), 0, stream,
                     flat, wf1t, partial);
  hipLaunchKernelGGL(k_head, dim3(B_), dim3(512), 0, stream,
                     partial, bf1, Wf2, bf2, out);
}

// Round 16
// 305.645 us; speedup vs baseline: 1.0016x; 1.0016x over previous
//
#include <hip/hip_runtime.h>
#include <hip/hip_bf16.h>

#define B_ 256
#define N_ 784
#define E_ 6272
#define C_ 32
#define H_ 512
#define NK 25088            // N_*C_  (K of fc1; wf1t row stride)
#define KP 800              // padded src-dim AND padded dest-dim for Adj
#define S_SPLIT 28

typedef __attribute__((ext_vector_type(8))) short short8;
typedef __attribute__((ext_vector_type(4))) float f32x4;

__device__ __forceinline__ float elu1(float v) {
  return v > 0.f ? v : (__expf(v) - 1.f);
}

__device__ __forceinline__ unsigned short bf16b(float v) {
  __hip_bfloat16 h = __float2bfloat16(v);
  return *reinterpret_cast<unsigned short*>(&h);
}

__device__ __forceinline__ unsigned int pk2(float lo, float hi) {
  return (unsigned int)bf16b(lo) | ((unsigned int)bf16b(hi) << 16);
}

// ---- K0: block 0 = CSR; blocks 1..79 = zero Adj; blocks 80.. = Wf1 T part1 ----
__global__ __launch_bounds__(1024) void k_prep(
    const int* __restrict__ erow, const int* __restrict__ ecol,
    const float* __restrict__ eval, const float* __restrict__ Wf1,
    int* __restrict__ row_ptr, int* __restrict__ col_s, float* __restrict__ val_s,
    __hip_bfloat16* __restrict__ adj, __hip_bfloat16* __restrict__ wf1t) {
  const int t = threadIdx.x;
  if (blockIdx.x == 0) {
    __shared__ int cnt[N_];
    __shared__ int off[N_];
    __shared__ int bufA[1024];
    __shared__ int bufB[1024];
    if (t < N_) cnt[t] = 0;
    __syncthreads();
    for (int e = t; e < E_; e += 1024) atomicAdd(&cnt[erow[e]], 1);
    __syncthreads();
    bufA[t] = (t < N_) ? cnt[t] : 0;
    __syncthreads();
    int* src = bufA; int* dst = bufB;
    for (int d = 1; d < 1024; d <<= 1) {
      int v = src[t];
      if (t >= d) v += src[t - d];
      dst[t] = v;
      __syncthreads();
      int* tmp = src; src = dst; dst = tmp;
    }
    if (t < N_) {
      int ex = src[t] - cnt[t];
      off[t] = ex;
      row_ptr[t] = ex;
    }
    if (t == 0) row_ptr[N_] = E_;
    __syncthreads();
    for (int e = t; e < E_; e += 1024) {
      int r = erow[e];
      int p = atomicAdd(&off[r], 1);
      col_s[p] = ecol[e];
      val_s[p] = eval[e];
    }
  } else if (blockIdx.x <= 79) {
    // zero Adj [800][800] bf16 = 1,280,000 B
    size_t off16 = ((size_t)(blockIdx.x - 1) * 1024 + t) * 16;
    if (off16 < (size_t)KP * KP * 2) {
      int4 z = {0, 0, 0, 0};
      *reinterpret_cast<int4*>(reinterpret_cast<char*>(adj) + off16) = z;
    }
  } else {
    // Wf1 [25088][512] f32 -> wf1t [512][25088] bf16, k in [0, 12544)
    __shared__ float tile[64][65];
    int bid = blockIdx.x - 80;                 // 0..1567
    int k0 = (bid % 196) * 64, n0 = (bid / 196) * 64;
#pragma unroll
    for (int it = 0; it < 4; ++it) {
      int idx = it * 1024 + t;
      int k = idx >> 6, n = idx & 63;
      tile[k][n] = Wf1[(size_t)(k0 + k) * H_ + n0 + n];
    }
    __syncthreads();
#pragma unroll
    for (int it = 0; it < 2; ++it) {
      int idx = it * 1024 + t;
      int n = idx >> 5, kp = idx & 31;
      unsigned int v = pk2(tile[2 * kp][n], tile[2 * kp + 1][n]);
      *reinterpret_cast<unsigned int*>(
          wf1t + (size_t)(n0 + n) * NK + k0 + 2 * kp) = v;
    }
  }
}

// ---- K1: blocks [0,256): exact-f32 spmm1 + W1 + elu -> h1T[bc][src] (padded)
//      blocks [256,260): Adj scatter from CSR (row-owned, duplicate-safe)
//      blocks [260,1828): Wf1 T part2 (k in [12544, 25088)) ----
__global__ __launch_bounds__(256) void k_h1T(
    const float* __restrict__ x, const int* __restrict__ row_ptr,
    const int* __restrict__ col_s, const float* __restrict__ val_s,
    const float* __restrict__ W1, const float* __restrict__ b1,
    const float* __restrict__ Wf1, __hip_bfloat16* __restrict__ adj,
    __hip_bfloat16* __restrict__ wf1t, __hip_bfloat16* __restrict__ h1T) {
  __shared__ float sm[64 * 65];       // union: xls[784]+aggls[784] | 64x65 tile
  int bid = blockIdx.x, t = threadIdx.x;
  if (bid < B_) {
    int b = bid;
    float* xls = sm;
    float* aggls = sm + N_;
    for (int i = t; i < N_; i += 256) xls[i] = x[(size_t)b * N_ + i];
    __syncthreads();
    for (int i = t; i < N_; i += 256) {
      int e0 = row_ptr[i], e1 = row_ptr[i + 1];
      float a = 0.f;
      for (int e = e0; e < e1; ++e) a = fmaf(val_s[e], xls[col_s[e]], a);
      aggls[i] = a;
    }
    __syncthreads();
#pragma unroll
    for (int c = 0; c < C_; ++c) {
      __hip_bfloat16* rowp = h1T + (size_t)(b * C_ + c) * KP;
      float wc = W1[c], bc = b1[c];
      for (int i = t; i < KP / 2; i += 256) {
        int n = 2 * i;
        float v0 = (n < N_) ? elu1(fmaf(aggls[n], wc, bc)) : 0.f;
        float v1 = (n + 1 < N_) ? elu1(fmaf(aggls[n + 1], wc, bc)) : 0.f;
        *reinterpret_cast<unsigned int*>(rowp + n) = pk2(v0, v1);
      }
    }
  } else if (bid < B_ + 4) {
    int n = (bid - B_) * 256 + t;
    if (n < N_) {
      int e0 = row_ptr[n], e1 = row_ptr[n + 1];
      for (int e = e0; e < e1; ++e) {
        __hip_bfloat16* p = adj + (size_t)n * KP + col_s[e];
        float cur = __bfloat162float(*p);
        *p = __float2bfloat16(cur + val_s[e]);
      }
    }
  } else {
    // Wf1 transpose: k0 in [12544, 25088), 64x64 tiles with 256 threads
    int bid2 = bid - (B_ + 4);                 // 0..1567
    int k0 = 12544 + (bid2 % 196) * 64, n0 = (bid2 / 196) * 64;
    float (*tile)[65] = reinterpret_cast<float(*)[65]>(sm);
#pragma unroll
    for (int it = 0; it < 16; ++it) {
      int idx = it * 256 + t;
      int kk = idx >> 6, nn = idx & 63;
      tile[kk][nn] = Wf1[(size_t)(k0 + kk) * H_ + n0 + nn];
    }
    __syncthreads();
#pragma unroll
    for (int it = 0; it < 8; ++it) {
      int idx = it * 256 + t;
      int nn = idx >> 5, kp = idx & 31;
      unsigned int v = pk2(tile[2 * kp][nn], tile[2 * kp + 1][nn]);
      *reinterpret_cast<unsigned int*>(
          wf1t + (size_t)(n0 + nn) * NK + k0 + 2 * kp) = v;
    }
  }
}

// ---- K2: spmm2 as dense MFMA GEMM + W2 + elu -> flat --------------------------
// C[m=dest 800pad][n=bc 32] = sum_k Adj[m][k] * h1T[n][k], K=800 (25 steps).
// grid (256 batches, 2 m-halves); block = 320 threads = 5 waves; wave owns 5
// m-frags (half covers 25 frags = 400 rows). Live set ~105 VGPR -> no spill.
// B (50KB) staged once via global_load_lds; A from L2 via 2-deep asm ring,
// vmcnt(5), never 0 mid-loop. Epilogue: acc->LDS, W2 in-register, bf16->flat.
__global__ __launch_bounds__(320, 1) void k_gemm2(
    const __hip_bfloat16* __restrict__ adj, const __hip_bfloat16* __restrict__ h1T,
    const float* __restrict__ W2, const float* __restrict__ b2,
    __hip_bfloat16* __restrict__ flat) {
  __shared__ alignas(16) unsigned char lds[61952];
  // [0,51200): B frags (50 x 1KB) | reused [0,57600): epilogue 5w x 5fm x 2304B
  // [57600,61824): W2 [32][33] f32 ; [61824,61952): b2
  int b = blockIdx.x, h = blockIdx.y;
  int tid = threadIdx.x;
  int w = tid >> 6, l = tid & 63;
  int r = l & 15, g = l >> 4;

  float* w2ls = reinterpret_cast<float*>(lds + 57600);
  float* b2ls = reinterpret_cast<float*>(lds + 61824);
  for (int i = tid; i < 1024; i += 320)
    w2ls[(i >> 5) * 33 + (i & 31)] = W2[i];
  if (tid < 32) b2ls[tid] = b2[tid];

  // stage B: 50 fragments (fn in {0,1} x ks in [0,25)); wave w stages w*10+i
#pragma unroll
  for (int i = 0; i < 10; ++i) {
    int f = w * 10 + i;
    int fn = f / 25, ks = f - fn * 25;
    __builtin_amdgcn_global_load_lds(
        (const __attribute__((address_space(1))) unsigned int*)
            (h1T + (size_t)(b * C_ + fn * 16 + r) * KP + ks * 32 + g * 8),
        (__attribute__((address_space(3))) unsigned int*)(lds + f * 1024 + l * 16),
        16, 0, 0);
  }
  __syncthreads();   // drains vmcnt+lgkmcnt; B ready, W2/b2 ready

  int rowbase = (h * 25 + w * 5) * 16 + r;
  const __hip_bfloat16* pa[5];
#pragma unroll
  for (int fm = 0; fm < 5; ++fm)
    pa[fm] = adj + (size_t)(rowbase + fm * 16) * KP + g * 8;

  f32x4 acc[5][2];
#pragma unroll
  for (int i = 0; i < 5; ++i)
#pragma unroll
    for (int j = 0; j < 2; ++j) acc[i][j] = (f32x4){0.f, 0.f, 0.f, 0.f};

  int4 va[2][5];

#define ALOAD(dst, ptr, imm)                                                  \
  asm volatile("global_load_dwordx4 %0, %1, off offset:%2"                    \
               : "=v"(dst) : "v"(ptr), "n"(imm))
#define AISSUE(s) do {                                                        \
    _Pragma("unroll")                                                         \
    for (int fm = 0; fm < 5; ++fm)                                            \
      ALOAD(va[(s) & 1][fm], pa[fm], (s) * 64);                               \
  } while (0)
#define AWAIT(n) do {                                                         \
    asm volatile("s_waitcnt vmcnt(%0)" :: "n"(n) : "memory");                 \
    __builtin_amdgcn_sched_barrier(0);                                        \
  } while (0)
#define ASTEP(t) do {                                                         \
    AWAIT((t) < 24 ? 5 : 0);                                                  \
    short8 _b0 = *reinterpret_cast<const short8*>(lds + (t) * 1024 + l * 16); \
    short8 _b1 = *reinterpret_cast<const short8*>(lds + (25 + (t)) * 1024 + l * 16); \
    _Pragma("unroll")                                                         \
    for (int fm = 0; fm < 5; ++fm) {                                          \
      short8 _a = *reinterpret_cast<short8*>(&va[(t) & 1][fm]);               \
      acc[fm][0] = __builtin_amdgcn_mfma_f32_16x16x32_bf16(_a, _b0, acc[fm][0], 0, 0, 0); \
      acc[fm][1] = __builtin_amdgcn_mfma_f32_16x16x32_bf16(_a, _b1, acc[fm][1], 0, 0, 0); \
    }                                                                         \
    if ((t) + 2 < 25) AISSUE((t) + 2);                                        \
  } while (0)

  AISSUE(0); AISSUE(1);
  ASTEP(0);  ASTEP(1);  ASTEP(2);  ASTEP(3);  ASTEP(4);
  ASTEP(5);  ASTEP(6);  ASTEP(7);  ASTEP(8);  ASTEP(9);
  ASTEP(10); ASTEP(11); ASTEP(12); ASTEP(13); ASTEP(14);
  ASTEP(15); ASTEP(16); ASTEP(17); ASTEP(18); ASTEP(19);
  ASTEP(20); ASTEP(21); ASTEP(22); ASTEP(23); ASTEP(24);

#undef ALOAD
#undef AISSUE
#undef AWAIT
#undef ASTEP

  __syncthreads();   // all waves done reading B before epilogue reuses [0,57600)

  // spill acc to per-wave LDS tiles: [fm][16 rows][36 cols] f32
  float* epf = reinterpret_cast<float*>(lds + w * 11520);
#pragma unroll
  for (int fm = 0; fm < 5; ++fm)
#pragma unroll
    for (int fn = 0; fn < 2; ++fn)
#pragma unroll
      for (int q = 0; q < 4; ++q)
        epf[fm * 576 + (g * 4 + q) * 36 + fn * 16 + r] = acc[fm][fn][q];
  __syncthreads();

  int row = l >> 2, cq = l & 3;   // lane -> (row in frag, c-quarter)
  float o[5][8];
#pragma unroll
  for (int fm = 0; fm < 5; ++fm)
#pragma unroll
    for (int j = 0; j < 8; ++j) o[fm][j] = b2ls[cq * 8 + j];

#pragma unroll
  for (int cb = 0; cb < 8; ++cb) {          // c blocks of 4
    float w2r[4][8];
#pragma unroll
    for (int cc = 0; cc < 4; ++cc)
#pragma unroll
      for (int j = 0; j < 8; ++j)
        w2r[cc][j] = w2ls[(cb * 4 + cc) * 33 + cq * 8 + j];
#pragma unroll
    for (int fm = 0; fm < 5; ++fm) {
      f32x4 a = *reinterpret_cast<f32x4*>(&epf[fm * 576 + row * 36 + cb * 4]);
#pragma unroll
      for (int cc = 0; cc < 4; ++cc)
#pragma unroll
        for (int j = 0; j < 8; ++j)
          o[fm][j] = fmaf(a[cc], w2r[cc][j], o[fm][j]);
    }
  }

#pragma unroll
  for (int fm = 0; fm < 5; ++fm) {
    int dest = (h * 25 + w * 5 + fm) * 16 + row;
    if (dest < N_) {
      union { unsigned short u[8]; int4 v; } ob;
#pragma unroll
      for (int j = 0; j < 8; ++j) ob.u[j] = bf16b(elu1(o[fm][j]));
      *reinterpret_cast<int4*>(flat + (size_t)b * NK + dest * C_ + cq * 8) = ob.v;
    }
  }
}

// ---------------- K3: fc1 split-K MFMA GEMM via global_load_lds pipeline ----------
// (unchanged from round 10 -- verified working)
__global__ __launch_bounds__(256, 2) void k_fc1(
    const __hip_bfloat16* __restrict__ flat, const __hip_bfloat16* __restrict__ wf1t,
    float* __restrict__ partial) {
  __shared__ unsigned char lds[3 * 24576];
  int raw = blockIdx.x;
  int bid = (raw & 7) * 56 + (raw >> 3);      // bijective XCD swizzle (448 = 8*56)
  int s = bid >> 4, r16 = bid & 15;
  int m0 = (r16 & 1) * 128;
  int n0 = (r16 >> 1) * 64;
  int k0 = s * 896;
  int tid = threadIdx.x;
  int w = tid >> 6, l = tid & 63;
  int r = l & 15, g = l >> 4;

  const __hip_bfloat16* src[6];
  int ldsoff[6];
#pragma unroll
  for (int j = 0; j < 6; ++j) {
    int reg = w * 6 + j;
    ldsoff[j] = reg * 1024 + l * 16;
    if (reg < 16) {
      int fmg = reg >> 1, ks = reg & 1;
      src[j] = flat + (size_t)(m0 + fmg * 16 + r) * NK + (k0 + ks * 32 + g * 8);
    } else {
      int fng = (reg - 16) >> 1, ks = reg & 1;
      src[j] = wf1t + (size_t)(n0 + fng * 16 + r) * NK + (k0 + ks * 32 + g * 8);
    }
  }

  f32x4 acc[4][2];
#pragma unroll
  for (int i = 0; i < 4; ++i)
#pragma unroll
    for (int j = 0; j < 2; ++j) acc[i][j] = (f32x4){0.f, 0.f, 0.f, 0.f};

#define GLOAD_LDS(gp, lp)                                                     \
  __builtin_amdgcn_global_load_lds(                                           \
      (const __attribute__((address_space(1))) unsigned int*)(gp),            \
      (__attribute__((address_space(3))) unsigned int*)(lp), 16, 0, 0)
#define STAGE(t, buf) do {                                                    \
    _Pragma("unroll")                                                         \
    for (int j = 0; j < 6; ++j)                                               \
      GLOAD_LDS(src[j] + (t) * 64, &lds[(buf) * 24576 + ldsoff[j]]);          \
  } while (0)
#define VWAIT(n) do {                                                         \
    asm volatile("s_waitcnt vmcnt(%0)" :: "n"(n) : "memory");                 \
    __builtin_amdgcn_sched_barrier(0);                                        \
  } while (0)
#define BAR() do {                                                            \
    __builtin_amdgcn_s_barrier();                                             \
    __builtin_amdgcn_sched_barrier(0);                                        \
  } while (0)
#define COMPUTE(buf) do {                                                     \
    const unsigned char* bb = &lds[(buf) * 24576];                            \
    short8 af[4][2], bf[2][2];                                                \
    _Pragma("unroll")                                                         \
    for (int fm = 0; fm < 4; ++fm)                                            \
      _Pragma("unroll")                                                       \
      for (int ks = 0; ks < 2; ++ks)                                          \
        af[fm][ks] = *reinterpret_cast<const short8*>(                        \
            bb + (((4 * (w & 1) + fm) * 2 + ks) << 10) + l * 16);             \
    _Pragma("unroll")                                                         \
    for (int fn = 0; fn < 2; ++fn)                                            \
      _Pragma("unroll")                                                       \
      for (int ks = 0; ks < 2; ++ks)                                          \
        bf[fn][ks] = *reinterpret_cast<const short8*>(                        \
            bb + ((16 + (2 * (w >> 1) + fn) * 2 + ks) << 10) + l * 16);       \
    _Pragma("unroll")                                                         \
    for (int ks = 0; ks < 2; ++ks)                                            \
      _Pragma("unroll")                                                       \
      for (int fn = 0; fn < 2; ++fn)                                          \
        _Pragma("unroll")                                                     \
        for (int fm = 0; fm < 4; ++fm)                                        \
          acc[fm][fn] = __builtin_amdgcn_mfma_f32_16x16x32_bf16(              \
              af[fm][ks], bf[fn][ks], acc[fm][fn], 0, 0, 0);                  \
  } while (0)
#define STEP(t) do {                                                          \
    VWAIT((t) < 13 ? 6 : 0);                                                  \
    BAR();                                                                    \
    if ((t) + 2 <= 13) STAGE((t) + 2, ((t) + 2) % 3);                         \
    COMPUTE((t) % 3);                                                         \
  } while (0)

  STAGE(0, 0);
  STAGE(1, 1);
  STEP(0);  STEP(1);  STEP(2);  STEP(3);  STEP(4);  STEP(5);  STEP(6);
  STEP(7);  STEP(8);  STEP(9);  STEP(10); STEP(11); STEP(12); STEP(13);

#undef GLOAD_LDS
#undef STAGE
#undef VWAIT
#undef BAR
#undef COMPUTE
#undef STEP

  int wm = (w & 1) * 64, wn = (w >> 1) * 32;
  float* p = partial + (size_t)s * (256 * 512);
#pragma unroll
  for (int fm = 0; fm < 4; ++fm)
#pragma unroll
    for (int fn = 0; fn < 2; ++fn)
#pragma unroll
      for (int q = 0; q < 4; ++q) {
        int m = m0 + wm + fm * 16 + g * 4 + q;
        int n = n0 + wn + fn * 16 + r;
        p[m * 512 + n] = acc[fm][fn][q];
      }
}

// ---------------- K4: reduce partials + bias + relu + fc2 + softmax ----------------
__global__ __launch_bounds__(512) void k_head(
    const float* __restrict__ partial, const float* __restrict__ bf1,
    const float* __restrict__ Wf2, const float* __restrict__ bf2,
    float* __restrict__ out) {
  __shared__ float red[8][12];
  int b = blockIdx.x;
  int t = threadIdx.x;
  float v = bf1[t];
#pragma unroll
  for (int s = 0; s < S_SPLIT; ++s)
    v += partial[(size_t)s * (256 * 512) + b * 512 + t];
  v = fmaxf(v, 0.f);
  float pacc[10];
#pragma unroll
  for (int j = 0; j < 10; ++j) pacc[j] = v * Wf2[t * 10 + j];
#pragma unroll
  for (int j = 0; j < 10; ++j)
#pragma unroll
    for (int d = 32; d > 0; d >>= 1)
      pacc[j] += __shfl_down(pacc[j], d);
  int wv = t >> 6, ln = t & 63;
  if (ln == 0) {
#pragma unroll
    for (int j = 0; j < 10; ++j) red[wv][j] = pacc[j];
  }
  __syncthreads();
  if (t == 0) {
    float lg[10];
    float m = -1e30f;
#pragma unroll
    for (int j = 0; j < 10; ++j) {
      float z = bf2[j];
#pragma unroll
      for (int wq = 0; wq < 8; ++wq) z += red[wq][j];
      lg[j] = z;
      m = fmaxf(m, z);
    }
    float sum = 0.f;
#pragma unroll
    for (int j = 0; j < 10; ++j) { lg[j] = __expf(lg[j] - m); sum += lg[j]; }
    float inv = 1.f / sum;
#pragma unroll
    for (int j = 0; j < 10; ++j) out[b * 10 + j] = lg[j] * inv;
  }
}

extern "C" void kernel_launch(void* const* d_in, const int* in_sizes, int n_in,
                              void* d_out, int out_size, void* d_ws, size_t ws_size,
                              hipStream_t stream) {
  const float* x    = (const float*)d_in[0];
  const int*   erow = (const int*)d_in[1];
  const int*   ecol = (const int*)d_in[2];
  const float* ev   = (const float*)d_in[3];
  const float* W1   = (const float*)d_in[4];
  const float* b1   = (const float*)d_in[5];
  const float* W2   = (const float*)d_in[6];
  const float* b2   = (const float*)d_in[7];
  const float* Wf1  = (const float*)d_in[8];
  const float* bf1  = (const float*)d_in[9];
  const float* Wf2  = (const float*)d_in[10];
  const float* bf2  = (const float*)d_in[11];
  float* out = (float*)d_out;

  const size_t partial_bytes = (size_t)S_SPLIT * 256 * 512 * 4;   // 14,680,064
  const size_t flat_bytes    = (size_t)B_ * NK * 2;               // 12,845,056
  const size_t wf1t_bytes    = (size_t)H_ * NK * 2;               // 25,690,112
  const size_t h1t_bytes     = (size_t)B_ * C_ * KP * 2;          // 13,107,200
  const size_t adj_bytes     = (size_t)KP * KP * 2;               //  1,280,000

  // disjoint layout (~67.6 MB; ws is ~268 MB)
  char* ws = (char*)d_ws;
  float* partial          = (float*)ws;
  __hip_bfloat16* flat    = (__hip_bfloat16*)(ws + partial_bytes);
  __hip_bfloat16* wf1t    = (__hip_bfloat16*)(ws + partial_bytes + flat_bytes);
  __hip_bfloat16* h1T     = (__hip_bfloat16*)(ws + partial_bytes + flat_bytes + wf1t_bytes);
  __hip_bfloat16* adj     = (__hip_bfloat16*)(ws + partial_bytes + flat_bytes + wf1t_bytes + h1t_bytes);
  char* tail = ws + partial_bytes + flat_bytes + wf1t_bytes + h1t_bytes + adj_bytes;
  int*   row_ptr = (int*)tail;
  int*   col_s   = (int*)(tail + 3152);
  float* val_s   = (float*)(tail + 3152 + E_ * 4);

  hipLaunchKernelGGL(k_prep, dim3(1 + 79 + 1568), dim3(1024), 0, stream,
                     erow, ecol, ev, Wf1, row_ptr, col_s, val_s, adj, wf1t);
  hipLaunchKernelGGL(k_h1T, dim3(B_ + 4 + 1568), dim3(256), 0, stream,
                     x, row_ptr, col_s, val_s, W1, b1, Wf1, adj, wf1t, h1T);
  hipLaunchKernelGGL(k_gemm2, dim3(B_, 2), dim3(320), 0, stream,
                     adj, h1T, W2, b2, flat);
  hipLaunchKernelGGL(k_fc1, dim3(S_SPLIT * 16), dim3(256), 0, stream,
                     flat, wf1t, partial);
  hipLaunchKernelGGL(k_head, dim3(B_), dim3(512), 0, stream,
                     partial, bf1, Wf2, bf2, out);
}

// Round 17
// 243.814 us; speedup vs baseline: 1.2557x; 1.2536x over previous
//
#include <hip/hip_runtime.h>
#include <hip/hip_bf16.h>

#define B_ 256
#define N_ 784
#define E_ 6272
#define C_ 32
#define H_ 512
#define NK 25088            // N_*C_  (K of fc1; wf1t row stride)
#define KP2 832             // padded src-dim for Adj/h1T (13 k-steps of 64)
#define MP 896              // padded dest-dim (7 m-tiles of 128)
#define S_SPLIT 28

typedef __attribute__((ext_vector_type(8))) short short8;
typedef __attribute__((ext_vector_type(4))) float f32x4;

__device__ __forceinline__ float elu1(float v) {
  return v > 0.f ? v : (__expf(v) - 1.f);
}

__device__ __forceinline__ unsigned short bf16b(float v) {
  __hip_bfloat16 h = __float2bfloat16(v);
  return *reinterpret_cast<unsigned short*>(&h);
}

__device__ __forceinline__ unsigned int pk2(float lo, float hi) {
  return (unsigned int)bf16b(lo) | ((unsigned int)bf16b(hi) << 16);
}

// ---- K0: block 0 = CSR; blocks 1..91 = zero Adj; blocks 92.. = Wf1 T part1 ----
__global__ __launch_bounds__(1024) void k_prep(
    const int* __restrict__ erow, const int* __restrict__ ecol,
    const float* __restrict__ eval, const float* __restrict__ Wf1,
    int* __restrict__ row_ptr, int* __restrict__ col_s, float* __restrict__ val_s,
    __hip_bfloat16* __restrict__ adj, __hip_bfloat16* __restrict__ wf1t) {
  const int t = threadIdx.x;
  if (blockIdx.x == 0) {
    __shared__ int cnt[N_];
    __shared__ int off[N_];
    __shared__ int bufA[1024];
    __shared__ int bufB[1024];
    if (t < N_) cnt[t] = 0;
    __syncthreads();
    for (int e = t; e < E_; e += 1024) atomicAdd(&cnt[erow[e]], 1);
    __syncthreads();
    bufA[t] = (t < N_) ? cnt[t] : 0;
    __syncthreads();
    int* src = bufA; int* dst = bufB;
    for (int d = 1; d < 1024; d <<= 1) {
      int v = src[t];
      if (t >= d) v += src[t - d];
      dst[t] = v;
      __syncthreads();
      int* tmp = src; src = dst; dst = tmp;
    }
    if (t < N_) {
      int ex = src[t] - cnt[t];
      off[t] = ex;
      row_ptr[t] = ex;
    }
    if (t == 0) row_ptr[N_] = E_;
    __syncthreads();
    for (int e = t; e < E_; e += 1024) {
      int r = erow[e];
      int p = atomicAdd(&off[r], 1);
      col_s[p] = ecol[e];
      val_s[p] = eval[e];
    }
  } else if (blockIdx.x <= 91) {
    // zero Adj [896][832] bf16 = 1,490,944 B (91 blocks x 16384 B)
    size_t off16 = ((size_t)(blockIdx.x - 1) * 1024 + t) * 16;
    if (off16 < (size_t)MP * KP2 * 2) {
      int4 z = {0, 0, 0, 0};
      *reinterpret_cast<int4*>(reinterpret_cast<char*>(adj) + off16) = z;
    }
  } else {
    // Wf1 [25088][512] f32 -> wf1t [512][25088] bf16, k in [0, 12544)
    __shared__ float tile[64][65];
    int bid = blockIdx.x - 92;                 // 0..1567
    int k0 = (bid % 196) * 64, n0 = (bid / 196) * 64;
#pragma unroll
    for (int it = 0; it < 4; ++it) {
      int idx = it * 1024 + t;
      int k = idx >> 6, n = idx & 63;
      tile[k][n] = Wf1[(size_t)(k0 + k) * H_ + n0 + n];
    }
    __syncthreads();
#pragma unroll
    for (int it = 0; it < 2; ++it) {
      int idx = it * 1024 + t;
      int n = idx >> 5, kp = idx & 31;
      unsigned int v = pk2(tile[2 * kp][n], tile[2 * kp + 1][n]);
      *reinterpret_cast<unsigned int*>(
          wf1t + (size_t)(n0 + n) * NK + k0 + 2 * kp) = v;
    }
  }
}

// ---- K1: blocks [0,256): exact-f32 spmm1 + W1 + elu -> h1T[bc][src] (pad 832)
//      blocks [256,260): Adj scatter from CSR (row-owned, duplicate-safe)
//      blocks [260,1828): Wf1 T part2 (k in [12544, 25088)) ----
__global__ __launch_bounds__(256) void k_h1T(
    const float* __restrict__ x, const int* __restrict__ row_ptr,
    const int* __restrict__ col_s, const float* __restrict__ val_s,
    const float* __restrict__ W1, const float* __restrict__ b1,
    const float* __restrict__ Wf1, __hip_bfloat16* __restrict__ adj,
    __hip_bfloat16* __restrict__ wf1t, __hip_bfloat16* __restrict__ h1T) {
  __shared__ float sm[64 * 65];       // union: xls[784]+aggls[784] | 64x65 tile
  int bid = blockIdx.x, t = threadIdx.x;
  if (bid < B_) {
    int b = bid;
    float* xls = sm;
    float* aggls = sm + N_;
    for (int i = t; i < N_; i += 256) xls[i] = x[(size_t)b * N_ + i];
    __syncthreads();
    for (int i = t; i < N_; i += 256) {
      int e0 = row_ptr[i], e1 = row_ptr[i + 1];
      float a = 0.f;
      for (int e = e0; e < e1; ++e) a = fmaf(val_s[e], xls[col_s[e]], a);
      aggls[i] = a;
    }
    __syncthreads();
#pragma unroll
    for (int c = 0; c < C_; ++c) {
      __hip_bfloat16* rowp = h1T + (size_t)(b * C_ + c) * KP2;
      float wc = W1[c], bc = b1[c];
      for (int i = t; i < KP2 / 2; i += 256) {
        int n = 2 * i;
        float v0 = (n < N_) ? elu1(fmaf(aggls[n], wc, bc)) : 0.f;
        float v1 = (n + 1 < N_) ? elu1(fmaf(aggls[n + 1], wc, bc)) : 0.f;
        *reinterpret_cast<unsigned int*>(rowp + n) = pk2(v0, v1);
      }
    }
  } else if (bid < B_ + 4) {
    int n = (bid - B_) * 256 + t;
    if (n < N_) {
      int e0 = row_ptr[n], e1 = row_ptr[n + 1];
      for (int e = e0; e < e1; ++e) {
        __hip_bfloat16* p = adj + (size_t)n * KP2 + col_s[e];
        float cur = __bfloat162float(*p);
        *p = __float2bfloat16(cur + val_s[e]);
      }
    }
  } else {
    // Wf1 transpose: k0 in [12544, 25088), 64x64 tiles with 256 threads
    int bid2 = bid - (B_ + 4);                 // 0..1567
    int k0 = 12544 + (bid2 % 196) * 64, n0 = (bid2 / 196) * 64;
    float (*tile)[65] = reinterpret_cast<float(*)[65]>(sm);
#pragma unroll
    for (int it = 0; it < 16; ++it) {
      int idx = it * 256 + t;
      int kk = idx >> 6, nn = idx & 63;
      tile[kk][nn] = Wf1[(size_t)(k0 + kk) * H_ + n0 + nn];
    }
    __syncthreads();
#pragma unroll
    for (int it = 0; it < 8; ++it) {
      int idx = it * 256 + t;
      int nn = idx >> 5, kp = idx & 31;
      unsigned int v = pk2(tile[2 * kp][nn], tile[2 * kp + 1][nn]);
      *reinterpret_cast<unsigned int*>(
          wf1t + (size_t)(n0 + nn) * NK + k0 + 2 * kp) = v;
    }
  }
}

// ---- K2: spmm2 as dense MFMA GEMM (fc1-template) + W2 + elu -> flat -----------
// C[m=dest MP][n=bc 8192] = sum_k Adj[m][k] * h1T[n][k], K=832 (13 steps of 64).
// BM=128, BN=64; grid = 7 mt x 128 nt = 896; 256 thr = 4 waves (2m x 2n).
// EXACT fc1 pipeline: 24 x 1KB fragment regions, 3 LDS buffers, global_load_lds,
// counted vmcnt(6), raw barriers. W2 epilogue AFTER the loop (W2 loaded to LDS
// post-loop so vmcnt arithmetic is untouched). Wave n-range 32 = one batch's
// channel block -> per-wave W2 apply, coalesced bf16 store to flat.
__global__ __launch_bounds__(256, 2) void k_gemm2(
    const __hip_bfloat16* __restrict__ adj, const __hip_bfloat16* __restrict__ h1T,
    const float* __restrict__ W2, const float* __restrict__ b2,
    __hip_bfloat16* __restrict__ flat) {
  __shared__ alignas(16) unsigned char lds[3 * 24576 + 4352];
  // [0, 73728): 3 staging buffers (24 regions x 1KB each)
  //             epilogue reuse: 4 waves x 9216 B acc tiles
  // [73728, 77952): W2 [32][33] f32 ; [77952, 78080): b2
  int bid = blockIdx.x;
  int mt = bid / 128, nt = bid % 128;
  int m0 = mt * 128, n0 = nt * 64;
  int tid = threadIdx.x;
  int w = tid >> 6, l = tid & 63;
  int r = l & 15, g = l >> 4;

  // This wave's 6 staging regions (region ids w*6+j of 24).
  const __hip_bfloat16* src[6];
  int ldsoff[6];
#pragma unroll
  for (int j = 0; j < 6; ++j) {
    int reg = w * 6 + j;
    ldsoff[j] = reg * 1024 + l * 16;
    if (reg < 16) {
      int fmg = reg >> 1, ks = reg & 1;
      src[j] = adj + (size_t)(m0 + fmg * 16 + r) * KP2 + (ks * 32 + g * 8);
    } else {
      int fng = (reg - 16) >> 1, ks = reg & 1;
      src[j] = h1T + (size_t)(n0 + fng * 16 + r) * KP2 + (ks * 32 + g * 8);
    }
  }

  f32x4 acc[4][2];
#pragma unroll
  for (int i = 0; i < 4; ++i)
#pragma unroll
    for (int j = 0; j < 2; ++j) acc[i][j] = (f32x4){0.f, 0.f, 0.f, 0.f};

#define GLOAD_LDS(gp, lp)                                                     \
  __builtin_amdgcn_global_load_lds(                                           \
      (const __attribute__((address_space(1))) unsigned int*)(gp),            \
      (__attribute__((address_space(3))) unsigned int*)(lp), 16, 0, 0)
#define STAGE(t, buf) do {                                                    \
    _Pragma("unroll")                                                         \
    for (int j = 0; j < 6; ++j)                                               \
      GLOAD_LDS(src[j] + (t) * 64, &lds[(buf) * 24576 + ldsoff[j]]);          \
  } while (0)
#define VWAIT(n) do {                                                         \
    asm volatile("s_waitcnt vmcnt(%0)" :: "n"(n) : "memory");                 \
    __builtin_amdgcn_sched_barrier(0);                                        \
  } while (0)
#define BAR() do {                                                            \
    __builtin_amdgcn_s_barrier();                                             \
    __builtin_amdgcn_sched_barrier(0);                                        \
  } while (0)
#define COMPUTE(buf) do {                                                     \
    const unsigned char* bb = &lds[(buf) * 24576];                            \
    short8 af[4][2], bf[2][2];                                                \
    _Pragma("unroll")                                                         \
    for (int fm = 0; fm < 4; ++fm)                                            \
      _Pragma("unroll")                                                       \
      for (int ks = 0; ks < 2; ++ks)                                          \
        af[fm][ks] = *reinterpret_cast<const short8*>(                        \
            bb + (((4 * (w & 1) + fm) * 2 + ks) << 10) + l * 16);             \
    _Pragma("unroll")                                                         \
    for (int fn = 0; fn < 2; ++fn)                                            \
      _Pragma("unroll")                                                       \
      for (int ks = 0; ks < 2; ++ks)                                          \
        bf[fn][ks] = *reinterpret_cast<const short8*>(                        \
            bb + ((16 + (2 * (w >> 1) + fn) * 2 + ks) << 10) + l * 16);       \
    _Pragma("unroll")                                                         \
    for (int ks = 0; ks < 2; ++ks)                                            \
      _Pragma("unroll")                                                       \
      for (int fn = 0; fn < 2; ++fn)                                          \
        _Pragma("unroll")                                                     \
        for (int fm = 0; fm < 4; ++fm)                                        \
          acc[fm][fn] = __builtin_amdgcn_mfma_f32_16x16x32_bf16(              \
              af[fm][ks], bf[fn][ks], acc[fm][fn], 0, 0, 0);                  \
  } while (0)
#define STEP(t) do {                                                          \
    VWAIT((t) < 12 ? 6 : 0);                                                  \
    BAR();                                                                    \
    if ((t) + 2 <= 12) STAGE((t) + 2, ((t) + 2) % 3);                         \
    COMPUTE((t) % 3);                                                         \
  } while (0)

  STAGE(0, 0);
  STAGE(1, 1);
  STEP(0);  STEP(1);  STEP(2);  STEP(3);  STEP(4);  STEP(5);  STEP(6);
  STEP(7);  STEP(8);  STEP(9);  STEP(10); STEP(11); STEP(12);

#undef GLOAD_LDS
#undef STAGE
#undef VWAIT
#undef BAR
#undef COMPUTE
#undef STEP

  __syncthreads();   // staging LDS dead; safe to reuse for epilogue

  // spill acc to per-wave LDS tiles: [fm][16 m-rows][36 pad cols] f32
  float* epf = reinterpret_cast<float*>(lds + w * 9216);
#pragma unroll
  for (int fm = 0; fm < 4; ++fm)
#pragma unroll
    for (int fn = 0; fn < 2; ++fn)
#pragma unroll
      for (int q = 0; q < 4; ++q)
        epf[fm * 576 + (g * 4 + q) * 36 + fn * 16 + r] = acc[fm][fn][q];

  // load W2/b2 to LDS (post-loop: doesn't disturb vmcnt arithmetic)
  float* w2ls = reinterpret_cast<float*>(lds + 73728);
  float* b2ls = reinterpret_cast<float*>(lds + 77952);
  for (int i = tid; i < 1024; i += 256)
    w2ls[(i >> 5) * 33 + (i & 31)] = W2[i];
  if (tid < 32) b2ls[tid] = b2[tid];
  __syncthreads();

  int row = l >> 2, cq = l & 3;   // lane -> (m-row in frag, c'-quarter)
  int b_wave = nt * 2 + (w >> 1); // this wave's batch
  float o[4][8];
#pragma unroll
  for (int fm = 0; fm < 4; ++fm)
#pragma unroll
    for (int j = 0; j < 8; ++j) o[fm][j] = b2ls[cq * 8 + j];

#pragma unroll
  for (int cb = 0; cb < 8; ++cb) {          // c blocks of 4
    float w2r[4][8];
#pragma unroll
    for (int cc = 0; cc < 4; ++cc)
#pragma unroll
      for (int j = 0; j < 8; ++j)
        w2r[cc][j] = w2ls[(cb * 4 + cc) * 33 + cq * 8 + j];
#pragma unroll
    for (int fm = 0; fm < 4; ++fm) {
      f32x4 a = *reinterpret_cast<f32x4*>(&epf[fm * 576 + row * 36 + cb * 4]);
#pragma unroll
      for (int cc = 0; cc < 4; ++cc)
#pragma unroll
        for (int j = 0; j < 8; ++j)
          o[fm][j] = fmaf(a[cc], w2r[cc][j], o[fm][j]);
    }
  }

#pragma unroll
  for (int fm = 0; fm < 4; ++fm) {
    int dest = m0 + (w & 1) * 64 + fm * 16 + row;
    if (dest < N_) {
      union { unsigned short u[8]; int4 v; } ob;
#pragma unroll
      for (int j = 0; j < 8; ++j) ob.u[j] = bf16b(elu1(o[fm][j]));
      *reinterpret_cast<int4*>(flat + (size_t)b_wave * NK + dest * C_ + cq * 8) = ob.v;
    }
  }
}

// ---------------- K3: fc1 split-K MFMA GEMM via global_load_lds pipeline ----------
// (unchanged from round 10 -- verified working)
__global__ __launch_bounds__(256, 2) void k_fc1(
    const __hip_bfloat16* __restrict__ flat, const __hip_bfloat16* __restrict__ wf1t,
    float* __restrict__ partial) {
  __shared__ unsigned char lds[3 * 24576];
  int raw = blockIdx.x;
  int bid = (raw & 7) * 56 + (raw >> 3);      // bijective XCD swizzle (448 = 8*56)
  int s = bid >> 4, r16 = bid & 15;
  int m0 = (r16 & 1) * 128;
  int n0 = (r16 >> 1) * 64;
  int k0 = s * 896;
  int tid = threadIdx.x;
  int w = tid >> 6, l = tid & 63;
  int r = l & 15, g = l >> 4;

  const __hip_bfloat16* src[6];
  int ldsoff[6];
#pragma unroll
  for (int j = 0; j < 6; ++j) {
    int reg = w * 6 + j;
    ldsoff[j] = reg * 1024 + l * 16;
    if (reg < 16) {
      int fmg = reg >> 1, ks = reg & 1;
      src[j] = flat + (size_t)(m0 + fmg * 16 + r) * NK + (k0 + ks * 32 + g * 8);
    } else {
      int fng = (reg - 16) >> 1, ks = reg & 1;
      src[j] = wf1t + (size_t)(n0 + fng * 16 + r) * NK + (k0 + ks * 32 + g * 8);
    }
  }

  f32x4 acc[4][2];
#pragma unroll
  for (int i = 0; i < 4; ++i)
#pragma unroll
    for (int j = 0; j < 2; ++j) acc[i][j] = (f32x4){0.f, 0.f, 0.f, 0.f};

#define GLOAD_LDS(gp, lp)                                                     \
  __builtin_amdgcn_global_load_lds(                                           \
      (const __attribute__((address_space(1))) unsigned int*)(gp),            \
      (__attribute__((address_space(3))) unsigned int*)(lp), 16, 0, 0)
#define STAGE(t, buf) do {                                                    \
    _Pragma("unroll")                                                         \
    for (int j = 0; j < 6; ++j)                                               \
      GLOAD_LDS(src[j] + (t) * 64, &lds[(buf) * 24576 + ldsoff[j]]);          \
  } while (0)
#define VWAIT(n) do {                                                         \
    asm volatile("s_waitcnt vmcnt(%0)" :: "n"(n) : "memory");                 \
    __builtin_amdgcn_sched_barrier(0);                                        \
  } while (0)
#define BAR() do {                                                            \
    __builtin_amdgcn_s_barrier();                                             \
    __builtin_amdgcn_sched_barrier(0);                                        \
  } while (0)
#define COMPUTE(buf) do {                                                     \
    const unsigned char* bb = &lds[(buf) * 24576];                            \
    short8 af[4][2], bf[2][2];                                                \
    _Pragma("unroll")                                                         \
    for (int fm = 0; fm < 4; ++fm)                                            \
      _Pragma("unroll")                                                       \
      for (int ks = 0; ks < 2; ++ks)                                          \
        af[fm][ks] = *reinterpret_cast<const short8*>(                        \
            bb + (((4 * (w & 1) + fm) * 2 + ks) << 10) + l * 16);             \
    _Pragma("unroll")                                                         \
    for (int fn = 0; fn < 2; ++fn)                                            \
      _Pragma("unroll")                                                       \
      for (int ks = 0; ks < 2; ++ks)                                          \
        bf[fn][ks] = *reinterpret_cast<const short8*>(                        \
            bb + ((16 + (2 * (w >> 1) + fn) * 2 + ks) << 10) + l * 16);       \
    _Pragma("unroll")                                                         \
    for (int ks = 0; ks < 2; ++ks)                                            \
      _Pragma("unroll")                                                       \
      for (int fn = 0; fn < 2; ++fn)                                          \
        _Pragma("unroll")                                                     \
        for (int fm = 0; fm < 4; ++fm)                                        \
          acc[fm][fn] = __builtin_amdgcn_mfma_f32_16x16x32_bf16(              \
              af[fm][ks], bf[fn][ks], acc[fm][fn], 0, 0, 0);                  \
  } while (0)
#define STEP(t) do {                                                          \
    VWAIT((t) < 13 ? 6 : 0);                                                  \
    BAR();                                                                    \
    if ((t) + 2 <= 13) STAGE((t) + 2, ((t) + 2) % 3);                         \
    COMPUTE((t) % 3);                                                         \
  } while (0)

  STAGE(0, 0);
  STAGE(1, 1);
  STEP(0);  STEP(1);  STEP(2);  STEP(3);  STEP(4);  STEP(5);  STEP(6);
  STEP(7);  STEP(8);  STEP(9);  STEP(10); STEP(11); STEP(12); STEP(13);

#undef GLOAD_LDS
#undef STAGE
#undef VWAIT
#undef BAR
#undef COMPUTE
#undef STEP

  int wm = (w & 1) * 64, wn = (w >> 1) * 32;
  float* p = partial + (size_t)s * (256 * 512);
#pragma unroll
  for (int fm = 0; fm < 4; ++fm)
#pragma unroll
    for (int fn = 0; fn < 2; ++fn)
#pragma unroll
      for (int q = 0; q < 4; ++q) {
        int m = m0 + wm + fm * 16 + g * 4 + q;
        int n = n0 + wn + fn * 16 + r;
        p[m * 512 + n] = acc[fm][fn][q];
      }
}

// ---------------- K4: reduce partials + bias + relu + fc2 + softmax ----------------
__global__ __launch_bounds__(512) void k_head(
    const float* __restrict__ partial, const float* __restrict__ bf1,
    const float* __restrict__ Wf2, const float* __restrict__ bf2,
    float* __restrict__ out) {
  __shared__ float red[8][12];
  int b = blockIdx.x;
  int t = threadIdx.x;
  float v = bf1[t];
#pragma unroll
  for (int s = 0; s < S_SPLIT; ++s)
    v += partial[(size_t)s * (256 * 512) + b * 512 + t];
  v = fmaxf(v, 0.f);
  float pacc[10];
#pragma unroll
  for (int j = 0; j < 10; ++j) pacc[j] = v * Wf2[t * 10 + j];
#pragma unroll
  for (int j = 0; j < 10; ++j)
#pragma unroll
    for (int d = 32; d > 0; d >>= 1)
      pacc[j] += __shfl_down(pacc[j], d);
  int wv = t >> 6, ln = t & 63;
  if (ln == 0) {
#pragma unroll
    for (int j = 0; j < 10; ++j) red[wv][j] = pacc[j];
  }
  __syncthreads();
  if (t == 0) {
    float lg[10];
    float m = -1e30f;
#pragma unroll
    for (int j = 0; j < 10; ++j) {
      float z = bf2[j];
#pragma unroll
      for (int wq = 0; wq < 8; ++wq) z += red[wq][j];
      lg[j] = z;
      m = fmaxf(m, z);
    }
    float sum = 0.f;
#pragma unroll
    for (int j = 0; j < 10; ++j) { lg[j] = __expf(lg[j] - m); sum += lg[j]; }
    float inv = 1.f / sum;
#pragma unroll
    for (int j = 0; j < 10; ++j) out[b * 10 + j] = lg[j] * inv;
  }
}

extern "C" void kernel_launch(void* const* d_in, const int* in_sizes, int n_in,
                              void* d_out, int out_size, void* d_ws, size_t ws_size,
                              hipStream_t stream) {
  const float* x    = (const float*)d_in[0];
  const int*   erow = (const int*)d_in[1];
  const int*   ecol = (const int*)d_in[2];
  const float* ev   = (const float*)d_in[3];
  const float* W1   = (const float*)d_in[4];
  const float* b1   = (const float*)d_in[5];
  const float* W2   = (const float*)d_in[6];
  const float* b2   = (const float*)d_in[7];
  const float* Wf1  = (const float*)d_in[8];
  const float* bf1  = (const float*)d_in[9];
  const float* Wf2  = (const float*)d_in[10];
  const float* bf2  = (const float*)d_in[11];
  float* out = (float*)d_out;

  const size_t partial_bytes = (size_t)S_SPLIT * 256 * 512 * 4;   // 14,680,064
  const size_t flat_bytes    = (size_t)B_ * NK * 2;               // 12,845,056
  const size_t wf1t_bytes    = (size_t)H_ * NK * 2;               // 25,690,112
  const size_t h1t_bytes     = (size_t)B_ * C_ * KP2 * 2;         // 13,631,488
  const size_t adj_bytes     = (size_t)MP * KP2 * 2;              //  1,490,944

  // disjoint layout (~68.3 MB; ws is ~268 MB)
  char* ws = (char*)d_ws;
  float* partial          = (float*)ws;
  __hip_bfloat16* flat    = (__hip_bfloat16*)(ws + partial_bytes);
  __hip_bfloat16* wf1t    = (__hip_bfloat16*)(ws + partial_bytes + flat_bytes);
  __hip_bfloat16* h1T     = (__hip_bfloat16*)(ws + partial_bytes + flat_bytes + wf1t_bytes);
  __hip_bfloat16* adj     = (__hip_bfloat16*)(ws + partial_bytes + flat_bytes + wf1t_bytes + h1t_bytes);
  char* tail = ws + partial_bytes + flat_bytes + wf1t_bytes + h1t_bytes + adj_bytes;
  int*   row_ptr = (int*)tail;
  int*   col_s   = (int*)(tail + 3152);
  float* val_s   = (float*)(tail + 3152 + E_ * 4);

  hipLaunchKernelGGL(k_prep, dim3(1 + 91 + 1568), dim3(1024), 0, stream,
                     erow, ecol, ev, Wf1, row_ptr, col_s, val_s, adj, wf1t);
  hipLaunchKernelGGL(k_h1T, dim3(B_ + 4 + 1568), dim3(256), 0, stream,
                     x, row_ptr, col_s, val_s, W1, b1, Wf1, adj, wf1t, h1T);
  hipLaunchKernelGGL(k_gemm2, dim3(7 * 128), dim3(256), 0, stream,
                     adj, h1T, W2, b2, flat);
  hipLaunchKernelGGL(k_fc1, dim3(S_SPLIT * 16), dim3(256), 0, stream,
                     flat, wf1t, partial);
  hipLaunchKernelGGL(k_head, dim3(B_), dim3(512), 0, stream,
                     partial, bf1, Wf2, bf2, out);
}

// Round 18
// 143.163 us; speedup vs baseline: 2.1384x; 1.7031x over previous
//
#include <hip/hip_runtime.h>
#include <hip/hip_bf16.h>

#define B_ 256
#define N_ 784
#define E_ 6272
#define C_ 32
#define H_ 512
#define NK 25088            // N_*C_  (K of fc1; wf1t row stride)
#define KP2 832             // padded src-dim for Adj/h1T (13 k-steps of 64)
#define MP 896              // padded dest-dim (7 m-tiles of 128)
#define BC2 8192            // B_*C_ = gemm2 N-dim / agg2 row stride
#define S_SPLIT 28

typedef __attribute__((ext_vector_type(8))) short short8;
typedef __attribute__((ext_vector_type(4))) float f32x4;

__device__ __forceinline__ float elu1(float v) {
  return v > 0.f ? v : (__expf(v) - 1.f);
}

__device__ __forceinline__ unsigned short bf16b(float v) {
  __hip_bfloat16 h = __float2bfloat16(v);
  return *reinterpret_cast<unsigned short*>(&h);
}

__device__ __forceinline__ unsigned int pk2(float lo, float hi) {
  return (unsigned int)bf16b(lo) | ((unsigned int)bf16b(hi) << 16);
}

// ---- K0: block 0 = CSR; blocks 1..91 = zero Adj; blocks 92.. = Wf1 T part1 ----
__global__ __launch_bounds__(1024) void k_prep(
    const int* __restrict__ erow, const int* __restrict__ ecol,
    const float* __restrict__ eval, const float* __restrict__ Wf1,
    int* __restrict__ row_ptr, int* __restrict__ col_s, float* __restrict__ val_s,
    __hip_bfloat16* __restrict__ adj, __hip_bfloat16* __restrict__ wf1t) {
  const int t = threadIdx.x;
  if (blockIdx.x == 0) {
    __shared__ int cnt[N_];
    __shared__ int off[N_];
    __shared__ int bufA[1024];
    __shared__ int bufB[1024];
    if (t < N_) cnt[t] = 0;
    __syncthreads();
    for (int e = t; e < E_; e += 1024) atomicAdd(&cnt[erow[e]], 1);
    __syncthreads();
    bufA[t] = (t < N_) ? cnt[t] : 0;
    __syncthreads();
    int* src = bufA; int* dst = bufB;
    for (int d = 1; d < 1024; d <<= 1) {
      int v = src[t];
      if (t >= d) v += src[t - d];
      dst[t] = v;
      __syncthreads();
      int* tmp = src; src = dst; dst = tmp;
    }
    if (t < N_) {
      int ex = src[t] - cnt[t];
      off[t] = ex;
      row_ptr[t] = ex;
    }
    if (t == 0) row_ptr[N_] = E_;
    __syncthreads();
    for (int e = t; e < E_; e += 1024) {
      int r = erow[e];
      int p = atomicAdd(&off[r], 1);
      col_s[p] = ecol[e];
      val_s[p] = eval[e];
    }
  } else if (blockIdx.x <= 91) {
    // zero Adj [896][832] bf16 = 1,490,944 B (91 blocks x 16384 B)
    size_t off16 = ((size_t)(blockIdx.x - 1) * 1024 + t) * 16;
    if (off16 < (size_t)MP * KP2 * 2) {
      int4 z = {0, 0, 0, 0};
      *reinterpret_cast<int4*>(reinterpret_cast<char*>(adj) + off16) = z;
    }
  } else {
    // Wf1 [25088][512] f32 -> wf1t [512][25088] bf16, k in [0, 12544)
    __shared__ float tile[64][65];
    int bid = blockIdx.x - 92;                 // 0..1567
    int k0 = (bid % 196) * 64, n0 = (bid / 196) * 64;
#pragma unroll
    for (int it = 0; it < 4; ++it) {
      int idx = it * 1024 + t;
      int k = idx >> 6, n = idx & 63;
      tile[k][n] = Wf1[(size_t)(k0 + k) * H_ + n0 + n];
    }
    __syncthreads();
#pragma unroll
    for (int it = 0; it < 2; ++it) {
      int idx = it * 1024 + t;
      int n = idx >> 5, kp = idx & 31;
      unsigned int v = pk2(tile[2 * kp][n], tile[2 * kp + 1][n]);
      *reinterpret_cast<unsigned int*>(
          wf1t + (size_t)(n0 + n) * NK + k0 + 2 * kp) = v;
    }
  }
}

// ---- K1: blocks [0,256): exact-f32 spmm1 + W1 + elu -> h1T[bc][src] (pad 832)
//      blocks [256,260): Adj scatter from CSR (row-owned, duplicate-safe)
//      blocks [260,1828): Wf1 T part2 (k in [12544, 25088)) ----
__global__ __launch_bounds__(256) void k_h1T(
    const float* __restrict__ x, const int* __restrict__ row_ptr,
    const int* __restrict__ col_s, const float* __restrict__ val_s,
    const float* __restrict__ W1, const float* __restrict__ b1,
    const float* __restrict__ Wf1, __hip_bfloat16* __restrict__ adj,
    __hip_bfloat16* __restrict__ wf1t, __hip_bfloat16* __restrict__ h1T) {
  __shared__ float sm[64 * 65];       // union: xls[784]+aggls[784] | 64x65 tile
  int bid = blockIdx.x, t = threadIdx.x;
  if (bid < B_) {
    int b = bid;
    float* xls = sm;
    float* aggls = sm + N_;
    for (int i = t; i < N_; i += 256) xls[i] = x[(size_t)b * N_ + i];
    __syncthreads();
    for (int i = t; i < N_; i += 256) {
      int e0 = row_ptr[i], e1 = row_ptr[i + 1];
      float a = 0.f;
      for (int e = e0; e < e1; ++e) a = fmaf(val_s[e], xls[col_s[e]], a);
      aggls[i] = a;
    }
    __syncthreads();
#pragma unroll
    for (int c = 0; c < C_; ++c) {
      __hip_bfloat16* rowp = h1T + (size_t)(b * C_ + c) * KP2;
      float wc = W1[c], bc = b1[c];
      for (int i = t; i < KP2 / 2; i += 256) {
        int n = 2 * i;
        float v0 = (n < N_) ? elu1(fmaf(aggls[n], wc, bc)) : 0.f;
        float v1 = (n + 1 < N_) ? elu1(fmaf(aggls[n + 1], wc, bc)) : 0.f;
        *reinterpret_cast<unsigned int*>(rowp + n) = pk2(v0, v1);
      }
    }
  } else if (bid < B_ + 4) {
    int n = (bid - B_) * 256 + t;
    if (n < N_) {
      int e0 = row_ptr[n], e1 = row_ptr[n + 1];
      for (int e = e0; e < e1; ++e) {
        __hip_bfloat16* p = adj + (size_t)n * KP2 + col_s[e];
        float cur = __bfloat162float(*p);
        *p = __float2bfloat16(cur + val_s[e]);
      }
    }
  } else {
    // Wf1 transpose: k0 in [12544, 25088), 64x64 tiles with 256 threads
    int bid2 = bid - (B_ + 4);                 // 0..1567
    int k0 = 12544 + (bid2 % 196) * 64, n0 = (bid2 / 196) * 64;
    float (*tile)[65] = reinterpret_cast<float(*)[65]>(sm);
#pragma unroll
    for (int it = 0; it < 16; ++it) {
      int idx = it * 256 + t;
      int kk = idx >> 6, nn = idx & 63;
      tile[kk][nn] = Wf1[(size_t)(k0 + kk) * H_ + n0 + nn];
    }
    __syncthreads();
#pragma unroll
    for (int it = 0; it < 8; ++it) {
      int idx = it * 256 + t;
      int nn = idx >> 5, kp = idx & 31;
      unsigned int v = pk2(tile[2 * kp][nn], tile[2 * kp + 1][nn]);
      *reinterpret_cast<unsigned int*>(
          wf1t + (size_t)(n0 + nn) * NK + k0 + 2 * kp) = v;
    }
  }
}

// ---- K2: spmm2 as dense MFMA GEMM -- PURE fc1 clone, NO epilogue --------------
// agg2[m 896][n 8192] = sum_k Adj[m][k] * h1T[n][k], K=832 (13 steps of 64).
// BM=128, BN=64; grid = 7mt x 128nt = 896 (shift-decomposed); 256 thr = 4 waves.
// Identical pipeline to k_fc1: 24 x 1KB fragment regions, 3 LDS buffers,
// global_load_lds, counted vmcnt(6), raw barriers, f32 direct store.
__global__ __launch_bounds__(256, 2) void k_gemm2(
    const __hip_bfloat16* __restrict__ adj, const __hip_bfloat16* __restrict__ h1T,
    float* __restrict__ agg2) {
  __shared__ unsigned char lds[3 * 24576];
  int bid = blockIdx.x;
  int mt = bid >> 7, nt = bid & 127;
  int m0 = mt * 128;
  int n0 = nt * 64;
  int tid = threadIdx.x;
  int w = tid >> 6, l = tid & 63;
  int r = l & 15, g = l >> 4;

  const __hip_bfloat16* src[6];
  int ldsoff[6];
#pragma unroll
  for (int j = 0; j < 6; ++j) {
    int reg = w * 6 + j;
    ldsoff[j] = reg * 1024 + l * 16;
    if (reg < 16) {
      int fmg = reg >> 1, ks = reg & 1;
      src[j] = adj + (size_t)(m0 + fmg * 16 + r) * KP2 + (ks * 32 + g * 8);
    } else {
      int fng = (reg - 16) >> 1, ks = reg & 1;
      src[j] = h1T + (size_t)(n0 + fng * 16 + r) * KP2 + (ks * 32 + g * 8);
    }
  }

  f32x4 acc[4][2];
#pragma unroll
  for (int i = 0; i < 4; ++i)
#pragma unroll
    for (int j = 0; j < 2; ++j) acc[i][j] = (f32x4){0.f, 0.f, 0.f, 0.f};

#define GLOAD_LDS(gp, lp)                                                     \
  __builtin_amdgcn_global_load_lds(                                           \
      (const __attribute__((address_space(1))) unsigned int*)(gp),            \
      (__attribute__((address_space(3))) unsigned int*)(lp), 16, 0, 0)
#define STAGE(t, buf) do {                                                    \
    _Pragma("unroll")                                                         \
    for (int j = 0; j < 6; ++j)                                               \
      GLOAD_LDS(src[j] + (t) * 64, &lds[(buf) * 24576 + ldsoff[j]]);          \
  } while (0)
#define VWAIT(n) do {                                                         \
    asm volatile("s_waitcnt vmcnt(%0)" :: "n"(n) : "memory");                 \
    __builtin_amdgcn_sched_barrier(0);                                        \
  } while (0)
#define BAR() do {                                                            \
    __builtin_amdgcn_s_barrier();                                             \
    __builtin_amdgcn_sched_barrier(0);                                        \
  } while (0)
#define COMPUTE(buf) do {                                                     \
    const unsigned char* bb = &lds[(buf) * 24576];                            \
    short8 af[4][2], bf[2][2];                                                \
    _Pragma("unroll")                                                         \
    for (int fm = 0; fm < 4; ++fm)                                            \
      _Pragma("unroll")                                                       \
      for (int ks = 0; ks < 2; ++ks)                                          \
        af[fm][ks] = *reinterpret_cast<const short8*>(                        \
            bb + (((4 * (w & 1) + fm) * 2 + ks) << 10) + l * 16);             \
    _Pragma("unroll")                                                         \
    for (int fn = 0; fn < 2; ++fn)                                            \
      _Pragma("unroll")                                                       \
      for (int ks = 0; ks < 2; ++ks)                                          \
        bf[fn][ks] = *reinterpret_cast<const short8*>(                        \
            bb + ((16 + (2 * (w >> 1) + fn) * 2 + ks) << 10) + l * 16);       \
    _Pragma("unroll")                                                         \
    for (int ks = 0; ks < 2; ++ks)                                            \
      _Pragma("unroll")                                                       \
      for (int fn = 0; fn < 2; ++fn)                                          \
        _Pragma("unroll")                                                     \
        for (int fm = 0; fm < 4; ++fm)                                        \
          acc[fm][fn] = __builtin_amdgcn_mfma_f32_16x16x32_bf16(              \
              af[fm][ks], bf[fn][ks], acc[fm][fn], 0, 0, 0);                  \
  } while (0)
#define STEP(t) do {                                                          \
    VWAIT((t) < 12 ? 6 : 0);                                                  \
    BAR();                                                                    \
    if ((t) + 2 <= 12) STAGE((t) + 2, ((t) + 2) % 3);                         \
    COMPUTE((t) % 3);                                                         \
  } while (0)

  STAGE(0, 0);
  STAGE(1, 1);
  STEP(0);  STEP(1);  STEP(2);  STEP(3);  STEP(4);  STEP(5);  STEP(6);
  STEP(7);  STEP(8);  STEP(9);  STEP(10); STEP(11); STEP(12);

#undef GLOAD_LDS
#undef STAGE
#undef VWAIT
#undef BAR
#undef COMPUTE
#undef STEP

  int wm = (w & 1) * 64, wn = (w >> 1) * 32;
  // D layout: col = lane&15 (=r) -> n; row = g*4 + q -> m  (same as fc1 store)
#pragma unroll
  for (int fm = 0; fm < 4; ++fm)
#pragma unroll
    for (int fn = 0; fn < 2; ++fn)
#pragma unroll
      for (int q = 0; q < 4; ++q) {
        int m = m0 + wm + fm * 16 + g * 4 + q;
        int n = n0 + wn + fn * 16 + r;
        agg2[(size_t)m * BC2 + n] = acc[fm][fn][q];
      }
}

// ---- K2b: W2 apply + elu + bf16 -> flat (elementwise, trivial pressure) -------
// block = dest node n; thread t = batch b. Reads agg2[n][b*32..+32] (128B/lane),
// writes flat[b][n*32..+32] (64B/lane).
__global__ __launch_bounds__(256) void k_w2(
    const float* __restrict__ agg2, const float* __restrict__ W2,
    const float* __restrict__ b2, __hip_bfloat16* __restrict__ flat) {
  __shared__ float w2s[C_][C_ + 1];
  __shared__ float b2s[C_];
  int n = blockIdx.x, t = threadIdx.x;
  for (int i = t; i < C_ * C_; i += 256) w2s[i >> 5][i & 31] = W2[i];
  if (t < C_) b2s[t] = b2[t];
  __syncthreads();
  const float* arow = agg2 + (size_t)n * BC2 + t * C_;
  float a[C_];
#pragma unroll
  for (int j = 0; j < 8; ++j) {
    f32x4 v = *reinterpret_cast<const f32x4*>(arow + j * 4);
    a[j * 4 + 0] = v[0]; a[j * 4 + 1] = v[1];
    a[j * 4 + 2] = v[2]; a[j * 4 + 3] = v[3];
  }
  union { unsigned short u[C_]; int4 v[4]; } ob;
#pragma unroll
  for (int c = 0; c < C_; c += 2) {
    float o0 = b2s[c], o1 = b2s[c + 1];
#pragma unroll
    for (int cc = 0; cc < C_; ++cc) {
      o0 = fmaf(a[cc], w2s[cc][c], o0);
      o1 = fmaf(a[cc], w2s[cc][c + 1], o1);
    }
    ob.u[c] = bf16b(elu1(o0));
    ob.u[c + 1] = bf16b(elu1(o1));
  }
  int4* dst = reinterpret_cast<int4*>(flat + (size_t)t * NK + n * C_);
#pragma unroll
  for (int j = 0; j < 4; ++j) dst[j] = ob.v[j];
}

// ---------------- K3: fc1 split-K MFMA GEMM via global_load_lds pipeline ----------
// (unchanged from round 10 -- verified working)
__global__ __launch_bounds__(256, 2) void k_fc1(
    const __hip_bfloat16* __restrict__ flat, const __hip_bfloat16* __restrict__ wf1t,
    float* __restrict__ partial) {
  __shared__ unsigned char lds[3 * 24576];
  int raw = blockIdx.x;
  int bid = (raw & 7) * 56 + (raw >> 3);      // bijective XCD swizzle (448 = 8*56)
  int s = bid >> 4, r16 = bid & 15;
  int m0 = (r16 & 1) * 128;
  int n0 = (r16 >> 1) * 64;
  int k0 = s * 896;
  int tid = threadIdx.x;
  int w = tid >> 6, l = tid & 63;
  int r = l & 15, g = l >> 4;

  const __hip_bfloat16* src[6];
  int ldsoff[6];
#pragma unroll
  for (int j = 0; j < 6; ++j) {
    int reg = w * 6 + j;
    ldsoff[j] = reg * 1024 + l * 16;
    if (reg < 16) {
      int fmg = reg >> 1, ks = reg & 1;
      src[j] = flat + (size_t)(m0 + fmg * 16 + r) * NK + (k0 + ks * 32 + g * 8);
    } else {
      int fng = (reg - 16) >> 1, ks = reg & 1;
      src[j] = wf1t + (size_t)(n0 + fng * 16 + r) * NK + (k0 + ks * 32 + g * 8);
    }
  }

  f32x4 acc[4][2];
#pragma unroll
  for (int i = 0; i < 4; ++i)
#pragma unroll
    for (int j = 0; j < 2; ++j) acc[i][j] = (f32x4){0.f, 0.f, 0.f, 0.f};

#define GLOAD_LDS(gp, lp)                                                     \
  __builtin_amdgcn_global_load_lds(                                           \
      (const __attribute__((address_space(1))) unsigned int*)(gp),            \
      (__attribute__((address_space(3))) unsigned int*)(lp), 16, 0, 0)
#define STAGE(t, buf) do {                                                    \
    _Pragma("unroll")                                                         \
    for (int j = 0; j < 6; ++j)                                               \
      GLOAD_LDS(src[j] + (t) * 64, &lds[(buf) * 24576 + ldsoff[j]]);          \
  } while (0)
#define VWAIT(n) do {                                                         \
    asm volatile("s_waitcnt vmcnt(%0)" :: "n"(n) : "memory");                 \
    __builtin_amdgcn_sched_barrier(0);                                        \
  } while (0)
#define BAR() do {                                                            \
    __builtin_amdgcn_s_barrier();                                             \
    __builtin_amdgcn_sched_barrier(0);                                        \
  } while (0)
#define COMPUTE(buf) do {                                                     \
    const unsigned char* bb = &lds[(buf) * 24576];                            \
    short8 af[4][2], bf[2][2];                                                \
    _Pragma("unroll")                                                         \
    for (int fm = 0; fm < 4; ++fm)                                            \
      _Pragma("unroll")                                                       \
      for (int ks = 0; ks < 2; ++ks)                                          \
        af[fm][ks] = *reinterpret_cast<const short8*>(                        \
            bb + (((4 * (w & 1) + fm) * 2 + ks) << 10) + l * 16);             \
    _Pragma("unroll")                                                         \
    for (int fn = 0; fn < 2; ++fn)                                            \
      _Pragma("unroll")                                                       \
      for (int ks = 0; ks < 2; ++ks)                                          \
        bf[fn][ks] = *reinterpret_cast<const short8*>(                        \
            bb + ((16 + (2 * (w >> 1) + fn) * 2 + ks) << 10) + l * 16);       \
    _Pragma("unroll")                                                         \
    for (int ks = 0; ks < 2; ++ks)                                            \
      _Pragma("unroll")                                                       \
      for (int fn = 0; fn < 2; ++fn)                                          \
        _Pragma("unroll")                                                     \
        for (int fm = 0; fm < 4; ++fm)                                        \
          acc[fm][fn] = __builtin_amdgcn_mfma_f32_16x16x32_bf16(              \
              af[fm][ks], bf[fn][ks], acc[fm][fn], 0, 0, 0);                  \
  } while (0)
#define STEP(t) do {                                                          \
    VWAIT((t) < 13 ? 6 : 0);                                                  \
    BAR();                                                                    \
    if ((t) + 2 <= 13) STAGE((t) + 2, ((t) + 2) % 3);                         \
    COMPUTE((t) % 3);                                                         \
  } while (0)

  STAGE(0, 0);
  STAGE(1, 1);
  STEP(0);  STEP(1);  STEP(2);  STEP(3);  STEP(4);  STEP(5);  STEP(6);
  STEP(7);  STEP(8);  STEP(9);  STEP(10); STEP(11); STEP(12); STEP(13);

#undef GLOAD_LDS
#undef STAGE
#undef VWAIT
#undef BAR
#undef COMPUTE
#undef STEP

  int wm = (w & 1) * 64, wn = (w >> 1) * 32;
  float* p = partial + (size_t)s * (256 * 512);
#pragma unroll
  for (int fm = 0; fm < 4; ++fm)
#pragma unroll
    for (int fn = 0; fn < 2; ++fn)
#pragma unroll
      for (int q = 0; q < 4; ++q) {
        int m = m0 + wm + fm * 16 + g * 4 + q;
        int n = n0 + wn + fn * 16 + r;
        p[m * 512 + n] = acc[fm][fn][q];
      }
}

// ---------------- K4: reduce partials + bias + relu + fc2 + softmax ----------------
__global__ __launch_bounds__(512) void k_head(
    const float* __restrict__ partial, const float* __restrict__ bf1,
    const float* __restrict__ Wf2, const float* __restrict__ bf2,
    float* __restrict__ out) {
  __shared__ float red[8][12];
  int b = blockIdx.x;
  int t = threadIdx.x;
  float v = bf1[t];
#pragma unroll
  for (int s = 0; s < S_SPLIT; ++s)
    v += partial[(size_t)s * (256 * 512) + b * 512 + t];
  v = fmaxf(v, 0.f);
  float pacc[10];
#pragma unroll
  for (int j = 0; j < 10; ++j) pacc[j] = v * Wf2[t * 10 + j];
#pragma unroll
  for (int j = 0; j < 10; ++j)
#pragma unroll
    for (int d = 32; d > 0; d >>= 1)
      pacc[j] += __shfl_down(pacc[j], d);
  int wv = t >> 6, ln = t & 63;
  if (ln == 0) {
#pragma unroll
    for (int j = 0; j < 10; ++j) red[wv][j] = pacc[j];
  }
  __syncthreads();
  if (t == 0) {
    float lg[10];
    float m = -1e30f;
#pragma unroll
    for (int j = 0; j < 10; ++j) {
      float z = bf2[j];
#pragma unroll
      for (int wq = 0; wq < 8; ++wq) z += red[wq][j];
      lg[j] = z;
      m = fmaxf(m, z);
    }
    float sum = 0.f;
#pragma unroll
    for (int j = 0; j < 10; ++j) { lg[j] = __expf(lg[j] - m); sum += lg[j]; }
    float inv = 1.f / sum;
#pragma unroll
    for (int j = 0; j < 10; ++j) out[b * 10 + j] = lg[j] * inv;
  }
}

extern "C" void kernel_launch(void* const* d_in, const int* in_sizes, int n_in,
                              void* d_out, int out_size, void* d_ws, size_t ws_size,
                              hipStream_t stream) {
  const float* x    = (const float*)d_in[0];
  const int*   erow = (const int*)d_in[1];
  const int*   ecol = (const int*)d_in[2];
  const float* ev   = (const float*)d_in[3];
  const float* W1   = (const float*)d_in[4];
  const float* b1   = (const float*)d_in[5];
  const float* W2   = (const float*)d_in[6];
  const float* b2   = (const float*)d_in[7];
  const float* Wf1  = (const float*)d_in[8];
  const float* bf1  = (const float*)d_in[9];
  const float* Wf2  = (const float*)d_in[10];
  const float* bf2  = (const float*)d_in[11];
  float* out = (float*)d_out;

  const size_t partial_bytes = (size_t)S_SPLIT * 256 * 512 * 4;   // 14,680,064
  const size_t flat_bytes    = (size_t)B_ * NK * 2;               // 12,845,056
  const size_t wf1t_bytes    = (size_t)H_ * NK * 2;               // 25,690,112
  const size_t h1t_bytes     = (size_t)B_ * C_ * KP2 * 2;         // 13,631,488
  const size_t adj_bytes     = (size_t)MP * KP2 * 2;              //  1,490,944
  const size_t agg2_bytes    = (size_t)MP * BC2 * 4;              // 29,360,128

  // disjoint layout (~98 MB; ws is ~268 MB)
  char* ws = (char*)d_ws;
  float* partial          = (float*)ws;
  __hip_bfloat16* flat    = (__hip_bfloat16*)(ws + partial_bytes);
  __hip_bfloat16* wf1t    = (__hip_bfloat16*)(ws + partial_bytes + flat_bytes);
  __hip_bfloat16* h1T     = (__hip_bfloat16*)(ws + partial_bytes + flat_bytes + wf1t_bytes);
  __hip_bfloat16* adj     = (__hip_bfloat16*)(ws + partial_bytes + flat_bytes + wf1t_bytes + h1t_bytes);
  float* agg2             = (float*)(ws + partial_bytes + flat_bytes + wf1t_bytes + h1t_bytes + adj_bytes);
  char* tail = ws + partial_bytes + flat_bytes + wf1t_bytes + h1t_bytes + adj_bytes + agg2_bytes;
  int*   row_ptr = (int*)tail;
  int*   col_s   = (int*)(tail + 3152);
  float* val_s   = (float*)(tail + 3152 + E_ * 4);

  hipLaunchKernelGGL(k_prep, dim3(1 + 91 + 1568), dim3(1024), 0, stream,
                     erow, ecol, ev, Wf1, row_ptr, col_s, val_s, adj, wf1t);
  hipLaunchKernelGGL(k_h1T, dim3(B_ + 4 + 1568), dim3(256), 0, stream,
                     x, row_ptr, col_s, val_s, W1, b1, Wf1, adj, wf1t, h1T);
  hipLaunchKernelGGL(k_gemm2, dim3(7 * 128), dim3(256), 0, stream,
                     adj, h1T, agg2);
  hipLaunchKernelGGL(k_w2, dim3(N_), dim3(256), 0, stream,
                     agg2, W2, b2, flat);
  hipLaunchKernelGGL(k_fc1, dim3(S_SPLIT * 16), dim3(256), 0, stream,
                     flat, wf1t, partial);
  hipLaunchKernelGGL(k_head, dim3(B_), dim3(512), 0, stream,
                     partial, bf1, Wf2, bf2, out);
}

// Round 19
// 142.444 us; speedup vs baseline: 2.1492x; 1.0050x over previous
//
#include <hip/hip_runtime.h>
#include <hip/hip_bf16.h>

#define B_ 256
#define N_ 784
#define E_ 6272
#define C_ 32
#define H_ 512
#define NK 25088            // N_*C_  (K of fc1; wf1t row stride)
#define KP2 832             // padded src-dim for Adj/h1T (13 k-steps of 64)
#define MP 896              // padded dest-dim (7 m-tiles of 128)
#define BC2 8192            // B_*C_ = gemm2 N-dim / agg2 row stride
#define S_SPLIT 28

typedef __attribute__((ext_vector_type(8))) short short8;
typedef __attribute__((ext_vector_type(4))) float f32x4;

__device__ __forceinline__ float elu1(float v) {
  return v > 0.f ? v : (__expf(v) - 1.f);
}

__device__ __forceinline__ unsigned short bf16b(float v) {
  __hip_bfloat16 h = __float2bfloat16(v);
  return *reinterpret_cast<unsigned short*>(&h);
}

__device__ __forceinline__ unsigned int pk2(float lo, float hi) {
  return (unsigned int)bf16b(lo) | ((unsigned int)bf16b(hi) << 16);
}

// ---- K0: block 0 = CSR; blocks 1..91 = zero Adj; blocks 92.. = Wf1 T part1 ----
__global__ __launch_bounds__(1024) void k_prep(
    const int* __restrict__ erow, const int* __restrict__ ecol,
    const float* __restrict__ eval, const float* __restrict__ Wf1,
    int* __restrict__ row_ptr, int* __restrict__ col_s, float* __restrict__ val_s,
    __hip_bfloat16* __restrict__ adj, __hip_bfloat16* __restrict__ wf1t) {
  const int t = threadIdx.x;
  if (blockIdx.x == 0) {
    __shared__ int cnt[N_];
    __shared__ int off[N_];
    __shared__ int bufA[1024];
    __shared__ int bufB[1024];
    if (t < N_) cnt[t] = 0;
    __syncthreads();
    for (int e = t; e < E_; e += 1024) atomicAdd(&cnt[erow[e]], 1);
    __syncthreads();
    bufA[t] = (t < N_) ? cnt[t] : 0;
    __syncthreads();
    int* src = bufA; int* dst = bufB;
    for (int d = 1; d < 1024; d <<= 1) {
      int v = src[t];
      if (t >= d) v += src[t - d];
      dst[t] = v;
      __syncthreads();
      int* tmp = src; src = dst; dst = tmp;
    }
    if (t < N_) {
      int ex = src[t] - cnt[t];
      off[t] = ex;
      row_ptr[t] = ex;
    }
    if (t == 0) row_ptr[N_] = E_;
    __syncthreads();
    for (int e = t; e < E_; e += 1024) {
      int r = erow[e];
      int p = atomicAdd(&off[r], 1);
      col_s[p] = ecol[e];
      val_s[p] = eval[e];
    }
  } else if (blockIdx.x <= 91) {
    // zero Adj [896][832] bf16 = 1,490,944 B (91 blocks x 16384 B)
    size_t off16 = ((size_t)(blockIdx.x - 1) * 1024 + t) * 16;
    if (off16 < (size_t)MP * KP2 * 2) {
      int4 z = {0, 0, 0, 0};
      *reinterpret_cast<int4*>(reinterpret_cast<char*>(adj) + off16) = z;
    }
  } else {
    // Wf1 [25088][512] f32 -> wf1t [512][25088] bf16, k in [0, 12544)
    __shared__ float tile[64][65];
    int bid = blockIdx.x - 92;                 // 0..1567
    int k0 = (bid % 196) * 64, n0 = (bid / 196) * 64;
#pragma unroll
    for (int it = 0; it < 4; ++it) {
      int idx = it * 1024 + t;
      int k = idx >> 6, n = idx & 63;
      tile[k][n] = Wf1[(size_t)(k0 + k) * H_ + n0 + n];
    }
    __syncthreads();
#pragma unroll
    for (int it = 0; it < 2; ++it) {
      int idx = it * 1024 + t;
      int n = idx >> 5, kp = idx & 31;
      unsigned int v = pk2(tile[2 * kp][n], tile[2 * kp + 1][n]);
      *reinterpret_cast<unsigned int*>(
          wf1t + (size_t)(n0 + n) * NK + k0 + 2 * kp) = v;
    }
  }
}

// ---- K1: blocks [0,256): exact-f32 spmm1 + W1 + elu -> h1T[bc][src] (pad 832)
//      blocks [256,260): Adj scatter from CSR (row-owned, duplicate-safe)
//      blocks [260,1828): Wf1 T part2 (k in [12544, 25088)) ----
__global__ __launch_bounds__(256) void k_h1T(
    const float* __restrict__ x, const int* __restrict__ row_ptr,
    const int* __restrict__ col_s, const float* __restrict__ val_s,
    const float* __restrict__ W1, const float* __restrict__ b1,
    const float* __restrict__ Wf1, __hip_bfloat16* __restrict__ adj,
    __hip_bfloat16* __restrict__ wf1t, __hip_bfloat16* __restrict__ h1T) {
  __shared__ float sm[64 * 65];       // union: xls[784]+aggls[784] | 64x65 tile
  int bid = blockIdx.x, t = threadIdx.x;
  if (bid < B_) {
    int b = bid;
    float* xls = sm;
    float* aggls = sm + N_;
    for (int i = t; i < N_; i += 256) xls[i] = x[(size_t)b * N_ + i];
    __syncthreads();
    for (int i = t; i < N_; i += 256) {
      int e0 = row_ptr[i], e1 = row_ptr[i + 1];
      float a = 0.f;
      for (int e = e0; e < e1; ++e) a = fmaf(val_s[e], xls[col_s[e]], a);
      aggls[i] = a;
    }
    __syncthreads();
#pragma unroll
    for (int c = 0; c < C_; ++c) {
      __hip_bfloat16* rowp = h1T + (size_t)(b * C_ + c) * KP2;
      float wc = W1[c], bc = b1[c];
      for (int i = t; i < KP2 / 2; i += 256) {
        int n = 2 * i;
        float v0 = (n < N_) ? elu1(fmaf(aggls[n], wc, bc)) : 0.f;
        float v1 = (n + 1 < N_) ? elu1(fmaf(aggls[n + 1], wc, bc)) : 0.f;
        *reinterpret_cast<unsigned int*>(rowp + n) = pk2(v0, v1);
      }
    }
  } else if (bid < B_ + 4) {
    int n = (bid - B_) * 256 + t;
    if (n < N_) {
      int e0 = row_ptr[n], e1 = row_ptr[n + 1];
      for (int e = e0; e < e1; ++e) {
        __hip_bfloat16* p = adj + (size_t)n * KP2 + col_s[e];
        float cur = __bfloat162float(*p);
        *p = __float2bfloat16(cur + val_s[e]);
      }
    }
  } else {
    // Wf1 transpose: k0 in [12544, 25088), 64x64 tiles with 256 threads
    int bid2 = bid - (B_ + 4);                 // 0..1567
    int k0 = 12544 + (bid2 % 196) * 64, n0 = (bid2 / 196) * 64;
    float (*tile)[65] = reinterpret_cast<float(*)[65]>(sm);
#pragma unroll
    for (int it = 0; it < 16; ++it) {
      int idx = it * 256 + t;
      int kk = idx >> 6, nn = idx & 63;
      tile[kk][nn] = Wf1[(size_t)(k0 + kk) * H_ + n0 + nn];
    }
    __syncthreads();
#pragma unroll
    for (int it = 0; it < 8; ++it) {
      int idx = it * 256 + t;
      int nn = idx >> 5, kp = idx & 31;
      unsigned int v = pk2(tile[2 * kp][nn], tile[2 * kp + 1][nn]);
      *reinterpret_cast<unsigned int*>(
          wf1t + (size_t)(n0 + nn) * NK + k0 + 2 * kp) = v;
    }
  }
}

// ---- K2: spmm2 as dense MFMA GEMM -- fc1 clone + XCD-L2 partitioning ----------
// agg2[m 896][n 8192] = sum_k Adj[m][k] * h1T[n][k], K=832 (13 steps of 64).
// BM=128, BN=64; grid = 896. XCD swizzle: x=raw&7, j=raw>>3; nt=x*16+(j&15),
// mt=j>>4. Each XCD sees 16 fixed n-tiles x all 7 m-tiles -> working set
// (adj 1.5MB + h1T slices 1.7MB) fits 4MB XCD L2; staging re-reads become
// L2 hits (286MB @ 34.5TB/s ~ 8us floor).
__global__ __launch_bounds__(256, 2) void k_gemm2(
    const __hip_bfloat16* __restrict__ adj, const __hip_bfloat16* __restrict__ h1T,
    float* __restrict__ agg2) {
  __shared__ unsigned char lds[3 * 24576];
  int raw = blockIdx.x;
  int xcd = raw & 7, j = raw >> 3;
  int nt = xcd * 16 + (j & 15);
  int mt = j >> 4;
  int m0 = mt * 128;
  int n0 = nt * 64;
  int tid = threadIdx.x;
  int w = tid >> 6, l = tid & 63;
  int r = l & 15, g = l >> 4;

  const __hip_bfloat16* src[6];
  int ldsoff[6];
#pragma unroll
  for (int j2 = 0; j2 < 6; ++j2) {
    int reg = w * 6 + j2;
    ldsoff[j2] = reg * 1024 + l * 16;
    if (reg < 16) {
      int fmg = reg >> 1, ks = reg & 1;
      src[j2] = adj + (size_t)(m0 + fmg * 16 + r) * KP2 + (ks * 32 + g * 8);
    } else {
      int fng = (reg - 16) >> 1, ks = reg & 1;
      src[j2] = h1T + (size_t)(n0 + fng * 16 + r) * KP2 + (ks * 32 + g * 8);
    }
  }

  f32x4 acc[4][2];
#pragma unroll
  for (int i = 0; i < 4; ++i)
#pragma unroll
    for (int j2 = 0; j2 < 2; ++j2) acc[i][j2] = (f32x4){0.f, 0.f, 0.f, 0.f};

#define GLOAD_LDS(gp, lp)                                                     \
  __builtin_amdgcn_global_load_lds(                                           \
      (const __attribute__((address_space(1))) unsigned int*)(gp),            \
      (__attribute__((address_space(3))) unsigned int*)(lp), 16, 0, 0)
#define STAGE(t, buf) do {                                                    \
    _Pragma("unroll")                                                         \
    for (int j2 = 0; j2 < 6; ++j2)                                            \
      GLOAD_LDS(src[j2] + (t) * 64, &lds[(buf) * 24576 + ldsoff[j2]]);        \
  } while (0)
#define VWAIT(n) do {                                                         \
    asm volatile("s_waitcnt vmcnt(%0)" :: "n"(n) : "memory");                 \
    __builtin_amdgcn_sched_barrier(0);                                        \
  } while (0)
#define BAR() do {                                                            \
    __builtin_amdgcn_s_barrier();                                             \
    __builtin_amdgcn_sched_barrier(0);                                        \
  } while (0)
#define COMPUTE(buf) do {                                                     \
    const unsigned char* bb = &lds[(buf) * 24576];                            \
    short8 af[4][2], bf[2][2];                                                \
    _Pragma("unroll")                                                         \
    for (int fm = 0; fm < 4; ++fm)                                            \
      _Pragma("unroll")                                                       \
      for (int ks = 0; ks < 2; ++ks)                                          \
        af[fm][ks] = *reinterpret_cast<const short8*>(                        \
            bb + (((4 * (w & 1) + fm) * 2 + ks) << 10) + l * 16);             \
    _Pragma("unroll")                                                         \
    for (int fn = 0; fn < 2; ++fn)                                            \
      _Pragma("unroll")                                                       \
      for (int ks = 0; ks < 2; ++ks)                                          \
        bf[fn][ks] = *reinterpret_cast<const short8*>(                        \
            bb + ((16 + (2 * (w >> 1) + fn) * 2 + ks) << 10) + l * 16);       \
    _Pragma("unroll")                                                         \
    for (int ks = 0; ks < 2; ++ks)                                            \
      _Pragma("unroll")                                                       \
      for (int fn = 0; fn < 2; ++fn)                                          \
        _Pragma("unroll")                                                     \
        for (int fm = 0; fm < 4; ++fm)                                        \
          acc[fm][fn] = __builtin_amdgcn_mfma_f32_16x16x32_bf16(              \
              af[fm][ks], bf[fn][ks], acc[fm][fn], 0, 0, 0);                  \
  } while (0)
#define STEP(t) do {                                                          \
    VWAIT((t) < 12 ? 6 : 0);                                                  \
    BAR();                                                                    \
    if ((t) + 2 <= 12) STAGE((t) + 2, ((t) + 2) % 3);                         \
    COMPUTE((t) % 3);                                                         \
  } while (0)

  STAGE(0, 0);
  STAGE(1, 1);
  STEP(0);  STEP(1);  STEP(2);  STEP(3);  STEP(4);  STEP(5);  STEP(6);
  STEP(7);  STEP(8);  STEP(9);  STEP(10); STEP(11); STEP(12);

#undef GLOAD_LDS
#undef STAGE
#undef VWAIT
#undef BAR
#undef COMPUTE
#undef STEP

  int wm = (w & 1) * 64, wn = (w >> 1) * 32;
#pragma unroll
  for (int fm = 0; fm < 4; ++fm)
#pragma unroll
    for (int fn = 0; fn < 2; ++fn)
#pragma unroll
      for (int q = 0; q < 4; ++q) {
        int m = m0 + wm + fm * 16 + g * 4 + q;
        int n = n0 + wn + fn * 16 + r;
        agg2[(size_t)m * BC2 + n] = acc[fm][fn][q];
      }
}

// ---- K2b: W2 apply + elu + bf16 -> flat (elementwise, trivial pressure) -------
__global__ __launch_bounds__(256) void k_w2(
    const float* __restrict__ agg2, const float* __restrict__ W2,
    const float* __restrict__ b2, __hip_bfloat16* __restrict__ flat) {
  __shared__ float w2s[C_][C_ + 1];
  __shared__ float b2s[C_];
  int n = blockIdx.x, t = threadIdx.x;
  for (int i = t; i < C_ * C_; i += 256) w2s[i >> 5][i & 31] = W2[i];
  if (t < C_) b2s[t] = b2[t];
  __syncthreads();
  const float* arow = agg2 + (size_t)n * BC2 + t * C_;
  float a[C_];
#pragma unroll
  for (int j = 0; j < 8; ++j) {
    f32x4 v = *reinterpret_cast<const f32x4*>(arow + j * 4);
    a[j * 4 + 0] = v[0]; a[j * 4 + 1] = v[1];
    a[j * 4 + 2] = v[2]; a[j * 4 + 3] = v[3];
  }
  union { unsigned short u[C_]; int4 v[4]; } ob;
#pragma unroll
  for (int c = 0; c < C_; c += 2) {
    float o0 = b2s[c], o1 = b2s[c + 1];
#pragma unroll
    for (int cc = 0; cc < C_; ++cc) {
      o0 = fmaf(a[cc], w2s[cc][c], o0);
      o1 = fmaf(a[cc], w2s[cc][c + 1], o1);
    }
    ob.u[c] = bf16b(elu1(o0));
    ob.u[c + 1] = bf16b(elu1(o1));
  }
  int4* dst = reinterpret_cast<int4*>(flat + (size_t)t * NK + n * C_);
#pragma unroll
  for (int j = 0; j < 4; ++j) dst[j] = ob.v[j];
}

// ---------------- K3: fc1 split-K MFMA GEMM via global_load_lds pipeline ----------
// (unchanged from round 10 -- verified working)
__global__ __launch_bounds__(256, 2) void k_fc1(
    const __hip_bfloat16* __restrict__ flat, const __hip_bfloat16* __restrict__ wf1t,
    float* __restrict__ partial) {
  __shared__ unsigned char lds[3 * 24576];
  int raw = blockIdx.x;
  int bid = (raw & 7) * 56 + (raw >> 3);      // bijective XCD swizzle (448 = 8*56)
  int s = bid >> 4, r16 = bid & 15;
  int m0 = (r16 & 1) * 128;
  int n0 = (r16 >> 1) * 64;
  int k0 = s * 896;
  int tid = threadIdx.x;
  int w = tid >> 6, l = tid & 63;
  int r = l & 15, g = l >> 4;

  const __hip_bfloat16* src[6];
  int ldsoff[6];
#pragma unroll
  for (int j = 0; j < 6; ++j) {
    int reg = w * 6 + j;
    ldsoff[j] = reg * 1024 + l * 16;
    if (reg < 16) {
      int fmg = reg >> 1, ks = reg & 1;
      src[j] = flat + (size_t)(m0 + fmg * 16 + r) * NK + (k0 + ks * 32 + g * 8);
    } else {
      int fng = (reg - 16) >> 1, ks = reg & 1;
      src[j] = wf1t + (size_t)(n0 + fng * 16 + r) * NK + (k0 + ks * 32 + g * 8);
    }
  }

  f32x4 acc[4][2];
#pragma unroll
  for (int i = 0; i < 4; ++i)
#pragma unroll
    for (int j = 0; j < 2; ++j) acc[i][j] = (f32x4){0.f, 0.f, 0.f, 0.f};

#define GLOAD_LDS(gp, lp)                                                     \
  __builtin_amdgcn_global_load_lds(                                           \
      (const __attribute__((address_space(1))) unsigned int*)(gp),            \
      (__attribute__((address_space(3))) unsigned int*)(lp), 16, 0, 0)
#define STAGE(t, buf) do {                                                    \
    _Pragma("unroll")                                                         \
    for (int j = 0; j < 6; ++j)                                               \
      GLOAD_LDS(src[j] + (t) * 64, &lds[(buf) * 24576 + ldsoff[j]]);          \
  } while (0)
#define VWAIT(n) do {                                                         \
    asm volatile("s_waitcnt vmcnt(%0)" :: "n"(n) : "memory");                 \
    __builtin_amdgcn_sched_barrier(0);                                        \
  } while (0)
#define BAR() do {                                                            \
    __builtin_amdgcn_s_barrier();                                             \
    __builtin_amdgcn_sched_barrier(0);                                        \
  } while (0)
#define COMPUTE(buf) do {                                                     \
    const unsigned char* bb = &lds[(buf) * 24576];                            \
    short8 af[4][2], bf[2][2];                                                \
    _Pragma("unroll")                                                         \
    for (int fm = 0; fm < 4; ++fm)                                            \
      _Pragma("unroll")                                                       \
      for (int ks = 0; ks < 2; ++ks)                                          \
        af[fm][ks] = *reinterpret_cast<const short8*>(                        \
            bb + (((4 * (w & 1) + fm) * 2 + ks) << 10) + l * 16);             \
    _Pragma("unroll")                                                         \
    for (int fn = 0; fn < 2; ++fn)                                            \
      _Pragma("unroll")                                                       \
      for (int ks = 0; ks < 2; ++ks)                                          \
        bf[fn][ks] = *reinterpret_cast<const short8*>(                        \
            bb + ((16 + (2 * (w >> 1) + fn) * 2 + ks) << 10) + l * 16);       \
    _Pragma("unroll")                                                         \
    for (int ks = 0; ks < 2; ++ks)                                            \
      _Pragma("unroll")                                                       \
      for (int fn = 0; fn < 2; ++fn)                                          \
        _Pragma("unroll")                                                     \
        for (int fm = 0; fm < 4; ++fm)                                        \
          acc[fm][fn] = __builtin_amdgcn_mfma_f32_16x16x32_bf16(              \
              af[fm][ks], bf[fn][ks], acc[fm][fn], 0, 0, 0);                  \
  } while (0)
#define STEP(t) do {                                                          \
    VWAIT((t) < 13 ? 6 : 0);                                                  \
    BAR();                                                                    \
    if ((t) + 2 <= 13) STAGE((t) + 2, ((t) + 2) % 3);                         \
    COMPUTE((t) % 3);                                                         \
  } while (0)

  STAGE(0, 0);
  STAGE(1, 1);
  STEP(0);  STEP(1);  STEP(2);  STEP(3);  STEP(4);  STEP(5);  STEP(6);
  STEP(7);  STEP(8);  STEP(9);  STEP(10); STEP(11); STEP(12); STEP(13);

#undef GLOAD_LDS
#undef STAGE
#undef VWAIT
#undef BAR
#undef COMPUTE
#undef STEP

  int wm = (w & 1) * 64, wn = (w >> 1) * 32;
  float* p = partial + (size_t)s * (256 * 512);
#pragma unroll
  for (int fm = 0; fm < 4; ++fm)
#pragma unroll
    for (int fn = 0; fn < 2; ++fn)
#pragma unroll
      for (int q = 0; q < 4; ++q) {
        int m = m0 + wm + fm * 16 + g * 4 + q;
        int n = n0 + wn + fn * 16 + r;
        p[m * 512 + n] = acc[fm][fn][q];
      }
}

// ---------------- K4: reduce partials + bias + relu + fc2 + softmax ----------------
__global__ __launch_bounds__(512) void k_head(
    const float* __restrict__ partial, const float* __restrict__ bf1,
    const float* __restrict__ Wf2, const float* __restrict__ bf2,
    float* __restrict__ out) {
  __shared__ float red[8][12];
  int b = blockIdx.x;
  int t = threadIdx.x;
  float v = bf1[t];
#pragma unroll
  for (int s = 0; s < S_SPLIT; ++s)
    v += partial[(size_t)s * (256 * 512) + b * 512 + t];
  v = fmaxf(v, 0.f);
  float pacc[10];
#pragma unroll
  for (int j = 0; j < 10; ++j) pacc[j] = v * Wf2[t * 10 + j];
#pragma unroll
  for (int j = 0; j < 10; ++j)
#pragma unroll
    for (int d = 32; d > 0; d >>= 1)
      pacc[j] += __shfl_down(pacc[j], d);
  int wv = t >> 6, ln = t & 63;
  if (ln == 0) {
#pragma unroll
    for (int j = 0; j < 10; ++j) red[wv][j] = pacc[j];
  }
  __syncthreads();
  if (t == 0) {
    float lg[10];
    float m = -1e30f;
#pragma unroll
    for (int j = 0; j < 10; ++j) {
      float z = bf2[j];
#pragma unroll
      for (int wq = 0; wq < 8; ++wq) z += red[wq][j];
      lg[j] = z;
      m = fmaxf(m, z);
    }
    float sum = 0.f;
#pragma unroll
    for (int j = 0; j < 10; ++j) { lg[j] = __expf(lg[j] - m); sum += lg[j]; }
    float inv = 1.f / sum;
#pragma unroll
    for (int j = 0; j < 10; ++j) out[b * 10 + j] = lg[j] * inv;
  }
}

extern "C" void kernel_launch(void* const* d_in, const int* in_sizes, int n_in,
                              void* d_out, int out_size, void* d_ws, size_t ws_size,
                              hipStream_t stream) {
  const float* x    = (const float*)d_in[0];
  const int*   erow = (const int*)d_in[1];
  const int*   ecol = (const int*)d_in[2];
  const float* ev   = (const float*)d_in[3];
  const float* W1   = (const float*)d_in[4];
  const float* b1   = (const float*)d_in[5];
  const float* W2   = (const float*)d_in[6];
  const float* b2   = (const float*)d_in[7];
  const float* Wf1  = (const float*)d_in[8];
  const float* bf1  = (const float*)d_in[9];
  const float* Wf2  = (const float*)d_in[10];
  const float* bf2  = (const float*)d_in[11];
  float* out = (float*)d_out;

  const size_t partial_bytes = (size_t)S_SPLIT * 256 * 512 * 4;   // 14,680,064
  const size_t flat_bytes    = (size_t)B_ * NK * 2;               // 12,845,056
  const size_t wf1t_bytes    = (size_t)H_ * NK * 2;               // 25,690,112
  const size_t h1t_bytes     = (size_t)B_ * C_ * KP2 * 2;         // 13,631,488
  const size_t adj_bytes     = (size_t)MP * KP2 * 2;              //  1,490,944
  const size_t agg2_bytes    = (size_t)MP * BC2 * 4;              // 29,360,128

  // disjoint layout (~98 MB; ws is ~268 MB)
  char* ws = (char*)d_ws;
  float* partial          = (float*)ws;
  __hip_bfloat16* flat    = (__hip_bfloat16*)(ws + partial_bytes);
  __hip_bfloat16* wf1t    = (__hip_bfloat16*)(ws + partial_bytes + flat_bytes);
  __hip_bfloat16* h1T     = (__hip_bfloat16*)(ws + partial_bytes + flat_bytes + wf1t_bytes);
  __hip_bfloat16* adj     = (__hip_bfloat16*)(ws + partial_bytes + flat_bytes + wf1t_bytes + h1t_bytes);
  float* agg2             = (float*)(ws + partial_bytes + flat_bytes + wf1t_bytes + h1t_bytes + adj_bytes);
  char* tail = ws + partial_bytes + flat_bytes + wf1t_bytes + h1t_bytes + adj_bytes + agg2_bytes;
  int*   row_ptr = (int*)tail;
  int*   col_s   = (int*)(tail + 3152);
  float* val_s   = (float*)(tail + 3152 + E_ * 4);

  hipLaunchKernelGGL(k_prep, dim3(1 + 91 + 1568), dim3(1024), 0, stream,
                     erow, ecol, ev, Wf1, row_ptr, col_s, val_s, adj, wf1t);
  hipLaunchKernelGGL(k_h1T, dim3(B_ + 4 + 1568), dim3(256), 0, stream,
                     x, row_ptr, col_s, val_s, W1, b1, Wf1, adj, wf1t, h1T);
  hipLaunchKernelGGL(k_gemm2, dim3(MP / 128 * 128), dim3(256), 0, stream,
                     adj, h1T, agg2);
  hipLaunchKernelGGL(k_w2, dim3(N_), dim3(256), 0, stream,
                     agg2, W2, b2, flat);
  hipLaunchKernelGGL(k_fc1, dim3(S_SPLIT * 16), dim3(256), 0, stream,
                     flat, wf1t, partial);
  hipLaunchKernelGGL(k_head, dim3(B_), dim3(512), 0, stream,
                     partial, bf1, Wf2, bf2, out);
}